// Round 1
// baseline (831.748 us; speedup 1.0000x reference)
//
#include <hip/hip_runtime.h>

#define N_NODES 100000
#define N_EDGES 1600000
#define IN_DIM  128
#define HID_DIM 64
#define OUT_DIM 40

// ---------------- degree histogram (float atomics) ----------------
__global__ __launch_bounds__(256) void deg_kernel(const int* __restrict__ dst,
                                                  float* __restrict__ deg, int E) {
    int i = blockIdx.x * 256 + threadIdx.x;
    if (i < E) atomicAdd(&deg[dst[i]], 1.0f);
}

// deg -> deg^{-1/2} in place (self-loop adds +1)
__global__ __launch_bounds__(256) void dis_kernel(float* __restrict__ d, int n) {
    int i = blockIdx.x * 256 + threadIdx.x;
    if (i < n) d[i] = rsqrtf(d[i] + 1.0f);
}

// ---------------- tiled GEMM: Y[nrows,N] = X[nrows,K] @ W[K,N] ----------------
// 256 threads/block, ROWS rows per block. W staged fully in LDS, X tile in LDS.
// Thread grid: CG col-groups x (256/CG) row-groups; each thread: RT rows x CT cols.
template<int K, int N, int ROWS, int CG, int CT, int RT>
__global__ __launch_bounds__(256) void gemm_kernel(const float* __restrict__ X,
                                                   const float* __restrict__ W,
                                                   float* __restrict__ Y, int nrows) {
    __shared__ float Xs[ROWS][K + 1];
    __shared__ float Ws[K][N];
    const int tid = threadIdx.x;
    for (int i = tid; i < K * N; i += 256) Ws[i / N][i % N] = W[i];
    const int row0 = blockIdx.x * ROWS;
    for (int i = tid; i < ROWS * K; i += 256) {
        int r = i / K, c = i % K;
        int gr = row0 + r;
        Xs[r][c] = (gr < nrows) ? X[(long long)gr * K + c] : 0.0f;
    }
    __syncthreads();

    const int tx = tid % CG;   // col group
    const int ty = tid / CG;   // row group
    float acc[RT][CT];
#pragma unroll
    for (int i = 0; i < RT; ++i)
#pragma unroll
        for (int j = 0; j < CT; ++j) acc[i][j] = 0.0f;

#pragma unroll 4
    for (int k = 0; k < K; ++k) {
        float a[RT], b[CT];
#pragma unroll
        for (int i = 0; i < RT; ++i) a[i] = Xs[ty * RT + i][k];
#pragma unroll
        for (int j = 0; j < CT; ++j) b[j] = Ws[k][tx * CT + j];
#pragma unroll
        for (int i = 0; i < RT; ++i)
#pragma unroll
            for (int j = 0; j < CT; ++j) acc[i][j] += a[i] * b[j];
    }

#pragma unroll
    for (int i = 0; i < RT; ++i) {
        int gr = row0 + ty * RT + i;
        if (gr < nrows) {
#pragma unroll
            for (int j = 0; j < CT; ++j)
                Y[(long long)gr * N + tx * CT + j] = acc[i][j];
        }
    }
}

// ---------------- edge scatter, 64 features: one wave per edge ----------------
__global__ __launch_bounds__(256) void scatter64_kernel(const int* __restrict__ src,
                                                        const int* __restrict__ dst,
                                                        const float* __restrict__ dis,
                                                        const float* __restrict__ t,
                                                        float* __restrict__ agg, int E) {
    int idx = blockIdx.x * 256 + threadIdx.x;
    int e = idx >> 6, f = idx & 63;
    if (e < E) {
        int s = src[e], d = dst[e];
        float w = dis[s] * dis[d];
        atomicAdd(&agg[d * 64 + f], t[s * 64 + f] * w);
    }
}

// ---------------- edge scatter, 40 features ----------------
__global__ __launch_bounds__(256) void scatter40_kernel(const int* __restrict__ src,
                                                        const int* __restrict__ dst,
                                                        const float* __restrict__ dis,
                                                        const float* __restrict__ t,
                                                        float* __restrict__ agg, int E) {
    int idx = blockIdx.x * 256 + threadIdx.x;
    if (idx < E * 40) {
        int e = idx / 40;
        int f = idx - e * 40;
        int s = src[e], d = dst[e];
        float w = dis[s] * dis[d];
        atomicAdd(&agg[d * 40 + f], t[s * 40 + f] * w);
    }
}

// ---------------- self-loop + bias + relu (h written in place over agg) ----------------
__global__ __launch_bounds__(256) void relu_bias_kernel(float* __restrict__ agg,
                                                        const float* __restrict__ t,
                                                        const float* __restrict__ dis,
                                                        const float* __restrict__ b, int n) {
    int i = blockIdx.x * 256 + threadIdx.x;
    if (i < n) {
        int v = i >> 6;           // HID_DIM == 64
        int f = i & 63;
        float dv = dis[v];
        float val = agg[i] + t[i] * dv * dv + b[f];
        agg[i] = fmaxf(val, 0.0f);
    }
}

// ---------------- self-loop + bias + log_softmax over 40, in place in out ----------------
__global__ __launch_bounds__(256) void logsoftmax_kernel(float* __restrict__ out,
                                                         const float* __restrict__ t2,
                                                         const float* __restrict__ dis,
                                                         const float* __restrict__ b, int n) {
    int v = blockIdx.x * 256 + threadIdx.x;
    if (v < n) {
        float vals[OUT_DIM];
        float dv = dis[v];
        float dv2 = dv * dv;
        float m = -1e30f;
#pragma unroll
        for (int f = 0; f < OUT_DIM; ++f) {
            vals[f] = out[v * OUT_DIM + f] + t2[v * OUT_DIM + f] * dv2 + b[f];
            m = fmaxf(m, vals[f]);
        }
        float s = 0.0f;
#pragma unroll
        for (int f = 0; f < OUT_DIM; ++f) s += expf(vals[f] - m);
        float ls = logf(s);
#pragma unroll
        for (int f = 0; f < OUT_DIM; ++f) out[v * OUT_DIM + f] = vals[f] - m - ls;
    }
}

extern "C" void kernel_launch(void* const* d_in, const int* in_sizes, int n_in,
                              void* d_out, int out_size, void* d_ws, size_t ws_size,
                              hipStream_t stream) {
    const float* x  = (const float*)d_in[0];
    const int*   ei = (const int*)d_in[1];
    const float* W1 = (const float*)d_in[2];
    const float* b1 = (const float*)d_in[3];
    const float* W2 = (const float*)d_in[4];
    const float* b2 = (const float*)d_in[5];
    float* out = (float*)d_out;

    const int* src = ei;             // edge_index[0]
    const int* dst = ei + N_EDGES;   // edge_index[1]

    char* ws = (char*)d_ws;
    float* dis  = (float*)ws;                                  // 400 KB (deg then dis)
    float* t1   = (float*)(ws + (1 << 20));                    // 25.6 MB
    float* agg1 = (float*)(ws + (1 << 20) + 26214400);         // 25.6 MB (agg1 -> h)
    float* t2   = t1;                                          // reuse (t1 dead after relu)

    hipMemsetAsync(dis, 0, N_NODES * sizeof(float), stream);
    hipMemsetAsync(agg1, 0, (size_t)N_NODES * HID_DIM * sizeof(float), stream);
    hipMemsetAsync(out, 0, (size_t)N_NODES * OUT_DIM * sizeof(float), stream);

    deg_kernel<<<(N_EDGES + 255) / 256, 256, 0, stream>>>(dst, dis, N_EDGES);
    dis_kernel<<<(N_NODES + 255) / 256, 256, 0, stream>>>(dis, N_NODES);

    // layer 1: t1 = X @ W1
    gemm_kernel<128, 64, 32, 16, 4, 2>
        <<<(N_NODES + 31) / 32, 256, 0, stream>>>(x, W1, t1, N_NODES);
    scatter64_kernel<<<(N_EDGES * 64) / 256, 256, 0, stream>>>(src, dst, dis, t1, agg1, N_EDGES);
    relu_bias_kernel<<<(N_NODES * HID_DIM + 255) / 256, 256, 0, stream>>>(agg1, t1, dis, b1,
                                                                          N_NODES * HID_DIM);

    // layer 2: t2 = h @ W2 (h lives in agg1)
    gemm_kernel<64, 40, 64, 8, 5, 2>
        <<<(N_NODES + 63) / 64, 256, 0, stream>>>(agg1, W2, t2, N_NODES);
    scatter40_kernel<<<(N_EDGES * 40 + 255) / 256, 256, 0, stream>>>(src, dst, dis, t2, out, N_EDGES);
    logsoftmax_kernel<<<(N_NODES + 255) / 256, 256, 0, stream>>>(out, t2, dis, b2, N_NODES);
}

// Round 2
// 654.311 us; speedup vs baseline: 1.2712x; 1.2712x over previous
//
#include <hip/hip_runtime.h>

#define N_NODES 100000
#define N_EDGES 1600000
#define IN_DIM  128
#define HID_DIM 64
#define OUT_DIM 40

// ---------------- in-degree histogram (int atomics) ----------------
__global__ __launch_bounds__(256) void deg_kernel(const int* __restrict__ dst,
                                                  int* __restrict__ deg, int E) {
    int i = blockIdx.x * 256 + threadIdx.x;
    if (i < E) atomicAdd(&deg[dst[i]], 1);
}

// dis[v] = rsqrt(deg[v] + 1)  (self-loop)
__global__ __launch_bounds__(256) void dis_kernel(const int* __restrict__ deg,
                                                  float* __restrict__ dis, int n) {
    int i = blockIdx.x * 256 + threadIdx.x;
    if (i < n) dis[i] = rsqrtf((float)deg[i] + 1.0f);
}

// ---------------- single-block exclusive scan: deg -> rowptr, cursor ----------------
__global__ __launch_bounds__(1024) void scan_kernel(const int* __restrict__ deg,
                                                    int* __restrict__ rowptr,
                                                    int* __restrict__ cursor, int n) {
    __shared__ int sums[1024];
    const int t = threadIdx.x;
    const int CHUNK = (n + 1023) / 1024;
    const int base = t * CHUNK;
    int s = 0;
    for (int i = 0; i < CHUNK; ++i) {
        int idx = base + i;
        if (idx < n) s += deg[idx];
    }
    sums[t] = s;
    __syncthreads();
    // Hillis-Steele inclusive scan over 1024 partials
    for (int off = 1; off < 1024; off <<= 1) {
        int val = (t >= off) ? sums[t - off] : 0;
        __syncthreads();
        sums[t] += val;
        __syncthreads();
    }
    int run = (t > 0) ? sums[t - 1] : 0;  // exclusive prefix of this chunk
    for (int i = 0; i < CHUNK; ++i) {
        int idx = base + i;
        if (idx < n) {
            int d = deg[idx];
            rowptr[idx] = run;
            cursor[idx] = run;
            run += d;
        }
    }
    if (t == 1023) rowptr[n] = run;  // == E
}

// ---------------- CSR fill: csr_src grouped by dst ----------------
__global__ __launch_bounds__(256) void fill_kernel(const int* __restrict__ src,
                                                   const int* __restrict__ dst,
                                                   int* __restrict__ cursor,
                                                   int* __restrict__ csr, int E) {
    int e = blockIdx.x * 256 + threadIdx.x;
    if (e < E) {
        int d = dst[e];
        int pos = atomicAdd(&cursor[d], 1);
        csr[pos] = src[e];
    }
}

// ---------------- tiled GEMM with dis-scaling epilogue ----------------
// Y[r,:] = dis[r] * (X[r,:] @ W)
template<int K, int N, int ROWS, int CG, int CT, int RT>
__global__ __launch_bounds__(256) void gemm_kernel(const float* __restrict__ X,
                                                   const float* __restrict__ W,
                                                   const float* __restrict__ dis,
                                                   float* __restrict__ Y, int nrows) {
    __shared__ float Xs[ROWS][K + 1];
    __shared__ float Ws[K][N];
    const int tid = threadIdx.x;
    for (int i = tid; i < K * N; i += 256) Ws[i / N][i % N] = W[i];
    const int row0 = blockIdx.x * ROWS;
    for (int i = tid; i < ROWS * K; i += 256) {
        int r = i / K, c = i % K;
        int gr = row0 + r;
        Xs[r][c] = (gr < nrows) ? X[(long long)gr * K + c] : 0.0f;
    }
    __syncthreads();

    const int tx = tid % CG;
    const int ty = tid / CG;
    float acc[RT][CT];
#pragma unroll
    for (int i = 0; i < RT; ++i)
#pragma unroll
        for (int j = 0; j < CT; ++j) acc[i][j] = 0.0f;

#pragma unroll 4
    for (int k = 0; k < K; ++k) {
        float a[RT], b[CT];
#pragma unroll
        for (int i = 0; i < RT; ++i) a[i] = Xs[ty * RT + i][k];
#pragma unroll
        for (int j = 0; j < CT; ++j) b[j] = Ws[k][tx * CT + j];
#pragma unroll
        for (int i = 0; i < RT; ++i)
#pragma unroll
            for (int j = 0; j < CT; ++j) acc[i][j] += a[i] * b[j];
    }

#pragma unroll
    for (int i = 0; i < RT; ++i) {
        int gr = row0 + ty * RT + i;
        if (gr < nrows) {
            float dv = dis[gr];
#pragma unroll
            for (int j = 0; j < CT; ++j)
                Y[(long long)gr * N + tx * CT + j] = acc[i][j] * dv;
        }
    }
}

// ---------------- gather, 64 features: 16 threads/node, float4 each ----------------
// h[v] = relu(dis[v] * (sum_{u in N(v)} ts[u] + ts[v]) + b)
__global__ __launch_bounds__(256) void gather64_kernel(const int* __restrict__ rowptr,
                                                       const int* __restrict__ csr,
                                                       const float* __restrict__ ts,
                                                       const float* __restrict__ dis,
                                                       const float* __restrict__ b,
                                                       float* __restrict__ h, int n) {
    int tid = blockIdx.x * 256 + threadIdx.x;
    int v = tid >> 4, q = tid & 15;
    if (v >= n) return;
    const float4* tsv = (const float4*)ts;
    int beg = rowptr[v], end = rowptr[v + 1];
    float4 acc = tsv[v * 16 + q];  // self-loop term (ts already dis[v]-scaled)
    int j = beg;
    for (; j + 1 < end; j += 2) {
        int u0 = csr[j], u1 = csr[j + 1];
        float4 m0 = tsv[u0 * 16 + q];
        float4 m1 = tsv[u1 * 16 + q];
        acc.x += m0.x; acc.y += m0.y; acc.z += m0.z; acc.w += m0.w;
        acc.x += m1.x; acc.y += m1.y; acc.z += m1.z; acc.w += m1.w;
    }
    if (j < end) {
        int u = csr[j];
        float4 m = tsv[u * 16 + q];
        acc.x += m.x; acc.y += m.y; acc.z += m.z; acc.w += m.w;
    }
    float dv = dis[v];
    float4 bb = ((const float4*)b)[q];
    float4 r;
    r.x = fmaxf(acc.x * dv + bb.x, 0.0f);
    r.y = fmaxf(acc.y * dv + bb.y, 0.0f);
    r.z = fmaxf(acc.z * dv + bb.z, 0.0f);
    r.w = fmaxf(acc.w * dv + bb.w, 0.0f);
    ((float4*)h)[v * 16 + q] = r;
}

// ---------------- gather, 40 features: 10 threads/node, float4 each ----------------
// out[v] = dis[v] * (sum ts[u] + ts[v]) + b   (logits; log_softmax applied after)
__global__ __launch_bounds__(256) void gather40_kernel(const int* __restrict__ rowptr,
                                                       const int* __restrict__ csr,
                                                       const float* __restrict__ ts,
                                                       const float* __restrict__ dis,
                                                       const float* __restrict__ b,
                                                       float* __restrict__ out, int n) {
    int tid = blockIdx.x * 256 + threadIdx.x;
    int v = tid / 10, q = tid - v * 10;
    if (v >= n) return;
    const float4* tsv = (const float4*)ts;
    int beg = rowptr[v], end = rowptr[v + 1];
    float4 acc = tsv[v * 10 + q];
    int j = beg;
    for (; j + 1 < end; j += 2) {
        int u0 = csr[j], u1 = csr[j + 1];
        float4 m0 = tsv[u0 * 10 + q];
        float4 m1 = tsv[u1 * 10 + q];
        acc.x += m0.x; acc.y += m0.y; acc.z += m0.z; acc.w += m0.w;
        acc.x += m1.x; acc.y += m1.y; acc.z += m1.z; acc.w += m1.w;
    }
    if (j < end) {
        int u = csr[j];
        float4 m = tsv[u * 10 + q];
        acc.x += m.x; acc.y += m.y; acc.z += m.z; acc.w += m.w;
    }
    float dv = dis[v];
    float4 bb = ((const float4*)b)[q];
    float4 r;
    r.x = acc.x * dv + bb.x;
    r.y = acc.y * dv + bb.y;
    r.z = acc.z * dv + bb.z;
    r.w = acc.w * dv + bb.w;
    ((float4*)out)[v * 10 + q] = r;
}

// ---------------- log_softmax over 40, in place ----------------
__global__ __launch_bounds__(256) void logsoftmax_kernel(float* __restrict__ out, int n) {
    int v = blockIdx.x * 256 + threadIdx.x;
    if (v >= n) return;
    float4* rowp = (float4*)(out + (long long)v * OUT_DIM);
    float4 vals[10];
    float m = -1e30f;
#pragma unroll
    for (int i = 0; i < 10; ++i) {
        vals[i] = rowp[i];
        m = fmaxf(m, fmaxf(fmaxf(vals[i].x, vals[i].y), fmaxf(vals[i].z, vals[i].w)));
    }
    float s = 0.0f;
#pragma unroll
    for (int i = 0; i < 10; ++i) {
        s += expf(vals[i].x - m) + expf(vals[i].y - m) +
             expf(vals[i].z - m) + expf(vals[i].w - m);
    }
    float c = m + logf(s);
#pragma unroll
    for (int i = 0; i < 10; ++i) {
        vals[i].x -= c; vals[i].y -= c; vals[i].z -= c; vals[i].w -= c;
        rowp[i] = vals[i];
    }
}

extern "C" void kernel_launch(void* const* d_in, const int* in_sizes, int n_in,
                              void* d_out, int out_size, void* d_ws, size_t ws_size,
                              hipStream_t stream) {
    const float* x  = (const float*)d_in[0];
    const int*   ei = (const int*)d_in[1];
    const float* W1 = (const float*)d_in[2];
    const float* b1 = (const float*)d_in[3];
    const float* W2 = (const float*)d_in[4];
    const float* b2 = (const float*)d_in[5];
    float* out = (float*)d_out;

    const int* src = ei;             // edge_index[0]
    const int* dst = ei + N_EDGES;   // edge_index[1]

    // workspace layout (bytes):
    char* ws = (char*)d_ws;
    int*   deg    = (int*)ws;                          // 400 KB
    int*   rowptr = (int*)(ws + 512 * 1024);           // 400 KB (+1 entry)
    int*   cursor = (int*)(ws + 1024 * 1024);          // 400 KB
    float* dis    = (float*)(ws + 1536 * 1024);        // 400 KB
    int*   csr    = (int*)(ws + 2048 * 1024);          // 6.4 MB
    char*  ws2    = ws + 2048 * 1024 + 6553600;
    float* ts1    = (float*)ws2;                       // 25.6 MB (ts2 aliases prefix)
    float* h      = (float*)(ws2 + 26214400);          // 25.6 MB
    float* ts2    = ts1;                               // ts1 dead after gather64

    hipMemsetAsync(deg, 0, N_NODES * sizeof(int), stream);

    // CSR build (dst-grouped)
    deg_kernel<<<(N_EDGES + 255) / 256, 256, 0, stream>>>(dst, deg, N_EDGES);
    dis_kernel<<<(N_NODES + 255) / 256, 256, 0, stream>>>(deg, dis, N_NODES);
    scan_kernel<<<1, 1024, 0, stream>>>(deg, rowptr, cursor, N_NODES);
    fill_kernel<<<(N_EDGES + 255) / 256, 256, 0, stream>>>(src, dst, cursor, csr, N_EDGES);

    // layer 1: ts1 = dis * (X @ W1); h = relu(dis*(sum+self) + b1)
    gemm_kernel<128, 64, 32, 16, 4, 2>
        <<<(N_NODES + 31) / 32, 256, 0, stream>>>(x, W1, dis, ts1, N_NODES);
    gather64_kernel<<<(N_NODES * 16 + 255) / 256, 256, 0, stream>>>(rowptr, csr, ts1, dis, b1,
                                                                    h, N_NODES);

    // layer 2: ts2 = dis * (h @ W2); out = dis*(sum+self) + b2 -> log_softmax
    gemm_kernel<64, 40, 64, 8, 5, 2>
        <<<(N_NODES + 63) / 64, 256, 0, stream>>>(h, W2, dis, ts2, N_NODES);
    gather40_kernel<<<(N_NODES * 10 + 255) / 256, 256, 0, stream>>>(rowptr, csr, ts2, dis, b2,
                                                                    out, N_NODES);
    logsoftmax_kernel<<<(N_NODES + 255) / 256, 256, 0, stream>>>(out, N_NODES);
}

// Round 3
// 409.337 us; speedup vs baseline: 2.0319x; 1.5985x over previous
//
#include <hip/hip_runtime.h>

#define N_NODES 100000
#define N_EDGES 1600000
#define IN_DIM  128
#define HID_DIM 64
#define OUT_DIM 40

#define SCAN_CHUNK 1024
#define SCAN_NB ((N_NODES + SCAN_CHUNK - 1) / SCAN_CHUNK)   // 98

// ---------------- in-degree histogram (int atomics) ----------------
__global__ __launch_bounds__(256) void deg_kernel(const int* __restrict__ dst,
                                                  int* __restrict__ deg, int E) {
    int i = blockIdx.x * 256 + threadIdx.x;
    if (i < E) atomicAdd(&deg[dst[i]], 1);
}

// dis[v] = rsqrt(deg[v] + 1)  (self-loop)
__global__ __launch_bounds__(256) void dis_kernel(const int* __restrict__ deg,
                                                  float* __restrict__ dis, int n) {
    int i = blockIdx.x * 256 + threadIdx.x;
    if (i < n) dis[i] = rsqrtf((float)deg[i] + 1.0f);
}

// ---------------- hierarchical scan: deg -> rowptr/cursor ----------------
// phase 1: per-block (1024-elem chunk) sums
__global__ __launch_bounds__(256) void scan1_kernel(const int* __restrict__ deg,
                                                    int* __restrict__ bsum, int n) {
    __shared__ int red[256];
    int t = threadIdx.x;
    int base = blockIdx.x * SCAN_CHUNK + t * 4;
    int s = 0;
#pragma unroll
    for (int i = 0; i < 4; ++i) { int idx = base + i; if (idx < n) s += deg[idx]; }
    red[t] = s;
    __syncthreads();
    for (int off = 128; off > 0; off >>= 1) {
        if (t < off) red[t] += red[t + off];
        __syncthreads();
    }
    if (t == 0) bsum[blockIdx.x] = red[0];
}

// phase 2: single small block, exclusive scan of the block sums (nb <= 128)
__global__ __launch_bounds__(128) void scan2_kernel(int* __restrict__ bsum, int nb) {
    __shared__ int sh[128];
    int t = threadIdx.x;
    sh[t] = (t < nb) ? bsum[t] : 0;
    __syncthreads();
    for (int off = 1; off < 128; off <<= 1) {
        int val = (t >= off) ? sh[t - off] : 0;
        __syncthreads();
        sh[t] += val;
        __syncthreads();
    }
    if (t < nb) bsum[t] = (t > 0) ? sh[t - 1] : 0;
}

// phase 3: block-local exclusive scan + block offset -> rowptr, cursor
__global__ __launch_bounds__(256) void scan3_kernel(const int* __restrict__ deg,
                                                    const int* __restrict__ bsum,
                                                    int* __restrict__ rowptr,
                                                    int* __restrict__ cursor, int n) {
    __shared__ int sh[256];
    int t = threadIdx.x;
    int base = blockIdx.x * SCAN_CHUNK + t * 4;
    int d[4];
    int s = 0;
#pragma unroll
    for (int i = 0; i < 4; ++i) {
        int idx = base + i;
        d[i] = (idx < n) ? deg[idx] : 0;
        s += d[i];
    }
    sh[t] = s;
    __syncthreads();
    for (int off = 1; off < 256; off <<= 1) {
        int val = (t >= off) ? sh[t - off] : 0;
        __syncthreads();
        sh[t] += val;
        __syncthreads();
    }
    int run = bsum[blockIdx.x] + ((t > 0) ? sh[t - 1] : 0);
#pragma unroll
    for (int i = 0; i < 4; ++i) {
        int idx = base + i;
        if (idx < n) {
            rowptr[idx] = run;
            cursor[idx] = run;
            run += d[i];
        }
    }
    if (blockIdx.x == 0 && t == 0) rowptr[n] = N_EDGES;  // total is static
}

// ---------------- CSR fill: csr_src grouped by dst ----------------
__global__ __launch_bounds__(256) void fill_kernel(const int* __restrict__ src,
                                                   const int* __restrict__ dst,
                                                   int* __restrict__ cursor,
                                                   int* __restrict__ csr, int E) {
    int e = blockIdx.x * 256 + threadIdx.x;
    if (e < E) {
        int d = dst[e];
        int pos = atomicAdd(&cursor[d], 1);
        csr[pos] = src[e];
    }
}

// ---------------- tiled GEMM with dis-scaling epilogue ----------------
// Y[r,:] = dis[r] * (X[r,:] @ W)
template<int K, int N, int ROWS, int CG, int CT, int RT>
__global__ __launch_bounds__(256) void gemm_kernel(const float* __restrict__ X,
                                                   const float* __restrict__ W,
                                                   const float* __restrict__ dis,
                                                   float* __restrict__ Y, int nrows) {
    __shared__ float Xs[ROWS][K + 1];
    __shared__ float Ws[K][N];
    const int tid = threadIdx.x;
    for (int i = tid; i < K * N; i += 256) Ws[i / N][i % N] = W[i];
    const int row0 = blockIdx.x * ROWS;
    for (int i = tid; i < ROWS * K; i += 256) {
        int r = i / K, c = i % K;
        int gr = row0 + r;
        Xs[r][c] = (gr < nrows) ? X[(long long)gr * K + c] : 0.0f;
    }
    __syncthreads();

    const int tx = tid % CG;
    const int ty = tid / CG;
    float acc[RT][CT];
#pragma unroll
    for (int i = 0; i < RT; ++i)
#pragma unroll
        for (int j = 0; j < CT; ++j) acc[i][j] = 0.0f;

#pragma unroll 4
    for (int k = 0; k < K; ++k) {
        float a[RT], b[CT];
#pragma unroll
        for (int i = 0; i < RT; ++i) a[i] = Xs[ty * RT + i][k];
#pragma unroll
        for (int j = 0; j < CT; ++j) b[j] = Ws[k][tx * CT + j];
#pragma unroll
        for (int i = 0; i < RT; ++i)
#pragma unroll
            for (int j = 0; j < CT; ++j) acc[i][j] += a[i] * b[j];
    }

#pragma unroll
    for (int i = 0; i < RT; ++i) {
        int gr = row0 + ty * RT + i;
        if (gr < nrows) {
            float dv = dis[gr];
#pragma unroll
            for (int j = 0; j < CT; ++j)
                Y[(long long)gr * N + tx * CT + j] = acc[i][j] * dv;
        }
    }
}

// ---------------- gather, 64 features: 16 threads/node, float4 each ----------------
// h[v] = relu(dis[v] * (sum_{u in N(v)} ts[u] + ts[v]) + b)
__global__ __launch_bounds__(256) void gather64_kernel(const int* __restrict__ rowptr,
                                                       const int* __restrict__ csr,
                                                       const float* __restrict__ ts,
                                                       const float* __restrict__ dis,
                                                       const float* __restrict__ b,
                                                       float* __restrict__ h, int n) {
    int tid = blockIdx.x * 256 + threadIdx.x;
    int v = tid >> 4, q = tid & 15;
    if (v >= n) return;
    const float4* tsv = (const float4*)ts;
    int beg = rowptr[v], end = rowptr[v + 1];
    float4 acc = tsv[v * 16 + q];  // self-loop term (ts already dis[v]-scaled)
    int j = beg;
    for (; j + 1 < end; j += 2) {
        int u0 = csr[j], u1 = csr[j + 1];
        float4 m0 = tsv[u0 * 16 + q];
        float4 m1 = tsv[u1 * 16 + q];
        acc.x += m0.x; acc.y += m0.y; acc.z += m0.z; acc.w += m0.w;
        acc.x += m1.x; acc.y += m1.y; acc.z += m1.z; acc.w += m1.w;
    }
    if (j < end) {
        int u = csr[j];
        float4 m = tsv[u * 16 + q];
        acc.x += m.x; acc.y += m.y; acc.z += m.z; acc.w += m.w;
    }
    float dv = dis[v];
    float4 bb = ((const float4*)b)[q];
    float4 r;
    r.x = fmaxf(acc.x * dv + bb.x, 0.0f);
    r.y = fmaxf(acc.y * dv + bb.y, 0.0f);
    r.z = fmaxf(acc.z * dv + bb.z, 0.0f);
    r.w = fmaxf(acc.w * dv + bb.w, 0.0f);
    ((float4*)h)[v * 16 + q] = r;
}

// ---------------- gather, 40 features: 10 threads/node, float4 each ----------------
// out[v] = dis[v] * (sum ts[u] + ts[v]) + b   (logits; log_softmax applied after)
__global__ __launch_bounds__(256) void gather40_kernel(const int* __restrict__ rowptr,
                                                       const int* __restrict__ csr,
                                                       const float* __restrict__ ts,
                                                       const float* __restrict__ dis,
                                                       const float* __restrict__ b,
                                                       float* __restrict__ out, int n) {
    int tid = blockIdx.x * 256 + threadIdx.x;
    int v = tid / 10, q = tid - v * 10;
    if (v >= n) return;
    const float4* tsv = (const float4*)ts;
    int beg = rowptr[v], end = rowptr[v + 1];
    float4 acc = tsv[v * 10 + q];
    int j = beg;
    for (; j + 1 < end; j += 2) {
        int u0 = csr[j], u1 = csr[j + 1];
        float4 m0 = tsv[u0 * 10 + q];
        float4 m1 = tsv[u1 * 10 + q];
        acc.x += m0.x; acc.y += m0.y; acc.z += m0.z; acc.w += m0.w;
        acc.x += m1.x; acc.y += m1.y; acc.z += m1.z; acc.w += m1.w;
    }
    if (j < end) {
        int u = csr[j];
        float4 m = tsv[u * 10 + q];
        acc.x += m.x; acc.y += m.y; acc.z += m.z; acc.w += m.w;
    }
    float dv = dis[v];
    float4 bb = ((const float4*)b)[q];
    float4 r;
    r.x = acc.x * dv + bb.x;
    r.y = acc.y * dv + bb.y;
    r.z = acc.z * dv + bb.z;
    r.w = acc.w * dv + bb.w;
    ((float4*)out)[v * 10 + q] = r;
}

// ---------------- log_softmax over 40, in place ----------------
__global__ __launch_bounds__(256) void logsoftmax_kernel(float* __restrict__ out, int n) {
    int v = blockIdx.x * 256 + threadIdx.x;
    if (v >= n) return;
    float4* rowp = (float4*)(out + (long long)v * OUT_DIM);
    float4 vals[10];
    float m = -1e30f;
#pragma unroll
    for (int i = 0; i < 10; ++i) {
        vals[i] = rowp[i];
        m = fmaxf(m, fmaxf(fmaxf(vals[i].x, vals[i].y), fmaxf(vals[i].z, vals[i].w)));
    }
    float s = 0.0f;
#pragma unroll
    for (int i = 0; i < 10; ++i) {
        s += expf(vals[i].x - m) + expf(vals[i].y - m) +
             expf(vals[i].z - m) + expf(vals[i].w - m);
    }
    float c = m + logf(s);
#pragma unroll
    for (int i = 0; i < 10; ++i) {
        vals[i].x -= c; vals[i].y -= c; vals[i].z -= c; vals[i].w -= c;
        rowp[i] = vals[i];
    }
}

extern "C" void kernel_launch(void* const* d_in, const int* in_sizes, int n_in,
                              void* d_out, int out_size, void* d_ws, size_t ws_size,
                              hipStream_t stream) {
    const float* x  = (const float*)d_in[0];
    const int*   ei = (const int*)d_in[1];
    const float* W1 = (const float*)d_in[2];
    const float* b1 = (const float*)d_in[3];
    const float* W2 = (const float*)d_in[4];
    const float* b2 = (const float*)d_in[5];
    float* out = (float*)d_out;

    const int* src = ei;             // edge_index[0]
    const int* dst = ei + N_EDGES;   // edge_index[1]

    // workspace layout (bytes):
    char* ws = (char*)d_ws;
    int*   deg    = (int*)ws;                          // 400 KB
    int*   rowptr = (int*)(ws + 512 * 1024);           // 400 KB (+1 entry)
    int*   cursor = (int*)(ws + 1024 * 1024);          // 400 KB
    float* dis    = (float*)(ws + 1536 * 1024);        // 400 KB
    int*   bsum   = (int*)(ws + 1984 * 1024);          // 512 B (98 entries)
    int*   csr    = (int*)(ws + 2048 * 1024);          // 6.4 MB
    char*  ws2    = ws + 2048 * 1024 + 6553600;
    float* ts1    = (float*)ws2;                       // 25.6 MB
    float* h      = (float*)(ws2 + 26214400);          // 25.6 MB
    float* ts2    = ts1;                               // ts1 dead after gather64

    hipMemsetAsync(deg, 0, N_NODES * sizeof(int), stream);

    // CSR build (dst-grouped)
    deg_kernel<<<(N_EDGES + 255) / 256, 256, 0, stream>>>(dst, deg, N_EDGES);
    dis_kernel<<<(N_NODES + 255) / 256, 256, 0, stream>>>(deg, dis, N_NODES);
    scan1_kernel<<<SCAN_NB, 256, 0, stream>>>(deg, bsum, N_NODES);
    scan2_kernel<<<1, 128, 0, stream>>>(bsum, SCAN_NB);
    scan3_kernel<<<SCAN_NB, 256, 0, stream>>>(deg, bsum, rowptr, cursor, N_NODES);
    fill_kernel<<<(N_EDGES + 255) / 256, 256, 0, stream>>>(src, dst, cursor, csr, N_EDGES);

    // layer 1: ts1 = dis * (X @ W1); h = relu(dis*(sum+self) + b1)
    gemm_kernel<128, 64, 32, 16, 4, 2>
        <<<(N_NODES + 31) / 32, 256, 0, stream>>>(x, W1, dis, ts1, N_NODES);
    gather64_kernel<<<(N_NODES * 16 + 255) / 256, 256, 0, stream>>>(rowptr, csr, ts1, dis, b1,
                                                                    h, N_NODES);

    // layer 2: ts2 = dis * (h @ W2); out = dis*(sum+self) + b2 -> log_softmax
    gemm_kernel<64, 40, 64, 8, 5, 2>
        <<<(N_NODES + 63) / 64, 256, 0, stream>>>(h, W2, dis, ts2, N_NODES);
    gather40_kernel<<<(N_NODES * 10 + 255) / 256, 256, 0, stream>>>(rowptr, csr, ts2, dis, b2,
                                                                    out, N_NODES);
    logsoftmax_kernel<<<(N_NODES + 255) / 256, 256, 0, stream>>>(out, N_NODES);
}

// Round 4
// 352.221 us; speedup vs baseline: 2.3614x; 1.1622x over previous
//
#include <hip/hip_runtime.h>

#define N_NODES 100000
#define N_EDGES 1600000
#define IN_DIM  128
#define HID_DIM 64
#define OUT_DIM 40

#define SCAN_CHUNK 1024
#define SCAN_NB ((N_NODES + SCAN_CHUNK - 1) / SCAN_CHUNK)   // 98

#define BUK_SHIFT 9
#define NBUK ((N_NODES + (1 << BUK_SHIFT) - 1) >> BUK_SHIFT)  // 196
#define PART_CHUNK 4096
#define PART_EPT 16     // PART_CHUNK / 256

// ---------------- in-degree histogram (int atomics) ----------------
__global__ __launch_bounds__(256) void deg_kernel(const int* __restrict__ dst,
                                                  int* __restrict__ deg, int E) {
    int i = blockIdx.x * 256 + threadIdx.x;
    if (i < E) atomicAdd(&deg[dst[i]], 1);
}

// dis[v] = rsqrt(deg[v] + 1)  (self-loop)
__global__ __launch_bounds__(256) void dis_kernel(const int* __restrict__ deg,
                                                  float* __restrict__ dis, int n) {
    int i = blockIdx.x * 256 + threadIdx.x;
    if (i < n) dis[i] = rsqrtf((float)deg[i] + 1.0f);
}

// ---------------- hierarchical scan: deg -> rowptr/cursor ----------------
__global__ __launch_bounds__(256) void scan1_kernel(const int* __restrict__ deg,
                                                    int* __restrict__ bsum, int n) {
    __shared__ int red[256];
    int t = threadIdx.x;
    int base = blockIdx.x * SCAN_CHUNK + t * 4;
    int s = 0;
#pragma unroll
    for (int i = 0; i < 4; ++i) { int idx = base + i; if (idx < n) s += deg[idx]; }
    red[t] = s;
    __syncthreads();
    for (int off = 128; off > 0; off >>= 1) {
        if (t < off) red[t] += red[t + off];
        __syncthreads();
    }
    if (t == 0) bsum[blockIdx.x] = red[0];
}

__global__ __launch_bounds__(128) void scan2_kernel(int* __restrict__ bsum, int nb) {
    __shared__ int sh[128];
    int t = threadIdx.x;
    sh[t] = (t < nb) ? bsum[t] : 0;
    __syncthreads();
    for (int off = 1; off < 128; off <<= 1) {
        int val = (t >= off) ? sh[t - off] : 0;
        __syncthreads();
        sh[t] += val;
        __syncthreads();
    }
    if (t < nb) bsum[t] = (t > 0) ? sh[t - 1] : 0;
}

__global__ __launch_bounds__(256) void scan3_kernel(const int* __restrict__ deg,
                                                    const int* __restrict__ bsum,
                                                    int* __restrict__ rowptr,
                                                    int* __restrict__ cursor, int n) {
    __shared__ int sh[256];
    int t = threadIdx.x;
    int base = blockIdx.x * SCAN_CHUNK + t * 4;
    int d[4];
    int s = 0;
#pragma unroll
    for (int i = 0; i < 4; ++i) {
        int idx = base + i;
        d[i] = (idx < n) ? deg[idx] : 0;
        s += d[i];
    }
    sh[t] = s;
    __syncthreads();
    for (int off = 1; off < 256; off <<= 1) {
        int val = (t >= off) ? sh[t - off] : 0;
        __syncthreads();
        sh[t] += val;
        __syncthreads();
    }
    int run = bsum[blockIdx.x] + ((t > 0) ? sh[t - 1] : 0);
#pragma unroll
    for (int i = 0; i < 4; ++i) {
        int idx = base + i;
        if (idx < n) {
            rowptr[idx] = run;
            cursor[idx] = run;
            run += d[i];
        }
    }
    if (blockIdx.x == 0 && t == 0) rowptr[n] = N_EDGES;  // total is static
}

// cursorA[b] = rowptr[b * 512]  (bucket base offsets in csr/buk space)
__global__ __launch_bounds__(256) void bukinit_kernel(const int* __restrict__ rowptr,
                                                      int* __restrict__ cursorA) {
    int b = blockIdx.x * 256 + threadIdx.x;
    if (b < NBUK) cursorA[b] = rowptr[b << BUK_SHIFT];
}

// ---------------- pass A: partition edges into dst-buckets ----------------
__global__ __launch_bounds__(256) void partA_kernel(const int* __restrict__ src,
                                                    const int* __restrict__ dst,
                                                    int* __restrict__ cursorA,
                                                    int2* __restrict__ buk, int E) {
    __shared__ int hist[NBUK];
    __shared__ int base[NBUK];
    const int t = threadIdx.x;
    const int e0 = blockIdx.x * PART_CHUNK;
    for (int i = t; i < NBUK; i += 256) hist[i] = 0;
    __syncthreads();
    int mys[PART_EPT], myd[PART_EPT];
#pragma unroll
    for (int i = 0; i < PART_EPT; ++i) {
        int e = e0 + t + i * 256;
        if (e < E) {
            mys[i] = src[e];
            myd[i] = dst[e];
            atomicAdd(&hist[myd[i] >> BUK_SHIFT], 1);
        } else {
            myd[i] = -1;
        }
    }
    __syncthreads();
    for (int i = t; i < NBUK; i += 256)
        base[i] = (hist[i] > 0) ? atomicAdd(&cursorA[i], hist[i]) : 0;
    __syncthreads();
    for (int i = t; i < NBUK; i += 256) hist[i] = 0;
    __syncthreads();
#pragma unroll
    for (int i = 0; i < PART_EPT; ++i) {
        if (myd[i] >= 0) {
            int b = myd[i] >> BUK_SHIFT;
            int pos = base[b] + atomicAdd(&hist[b], 1);
            buk[pos] = make_int2(mys[i], myd[i]);
        }
    }
}

// ---------------- pass B: bucket-local scatter into csr ----------------
__global__ __launch_bounds__(256) void partB_kernel(const int2* __restrict__ buk,
                                                    int* __restrict__ cursor,
                                                    int* __restrict__ csr, int E) {
    int i = blockIdx.x * 256 + threadIdx.x;
    if (i < E) {
        int2 e = buk[i];
        int pos = atomicAdd(&cursor[e.y], 1);
        csr[pos] = e.x;
    }
}

// ---------------- tiled GEMM with dis-scaling epilogue ----------------
template<int K, int N, int ROWS, int CG, int CT, int RT>
__global__ __launch_bounds__(256) void gemm_kernel(const float* __restrict__ X,
                                                   const float* __restrict__ W,
                                                   const float* __restrict__ dis,
                                                   float* __restrict__ Y, int nrows) {
    __shared__ float Xs[ROWS][K + 1];
    __shared__ float Ws[K][N];
    const int tid = threadIdx.x;
    for (int i = tid; i < K * N; i += 256) Ws[i / N][i % N] = W[i];
    const int row0 = blockIdx.x * ROWS;
    for (int i = tid; i < ROWS * K; i += 256) {
        int r = i / K, c = i % K;
        int gr = row0 + r;
        Xs[r][c] = (gr < nrows) ? X[(long long)gr * K + c] : 0.0f;
    }
    __syncthreads();

    const int tx = tid % CG;
    const int ty = tid / CG;
    float acc[RT][CT];
#pragma unroll
    for (int i = 0; i < RT; ++i)
#pragma unroll
        for (int j = 0; j < CT; ++j) acc[i][j] = 0.0f;

#pragma unroll 4
    for (int k = 0; k < K; ++k) {
        float a[RT], b[CT];
#pragma unroll
        for (int i = 0; i < RT; ++i) a[i] = Xs[ty * RT + i][k];
#pragma unroll
        for (int j = 0; j < CT; ++j) b[j] = Ws[k][tx * CT + j];
#pragma unroll
        for (int i = 0; i < RT; ++i)
#pragma unroll
            for (int j = 0; j < CT; ++j) acc[i][j] += a[i] * b[j];
    }

#pragma unroll
    for (int i = 0; i < RT; ++i) {
        int gr = row0 + ty * RT + i;
        if (gr < nrows) {
            float dv = dis[gr];
#pragma unroll
            for (int j = 0; j < CT; ++j)
                Y[(long long)gr * N + tx * CT + j] = acc[i][j] * dv;
        }
    }
}

// ---------------- gather, 64 features: 16 threads/node, float4 each ----------------
__global__ __launch_bounds__(256) void gather64_kernel(const int* __restrict__ rowptr,
                                                       const int* __restrict__ csr,
                                                       const float* __restrict__ ts,
                                                       const float* __restrict__ dis,
                                                       const float* __restrict__ b,
                                                       float* __restrict__ h, int n) {
    int tid = blockIdx.x * 256 + threadIdx.x;
    int v = tid >> 4, q = tid & 15;
    if (v >= n) return;
    const float4* tsv = (const float4*)ts;
    int beg = rowptr[v], end = rowptr[v + 1];
    float4 acc = tsv[v * 16 + q];  // self-loop term (ts already dis[v]-scaled)
    int j = beg;
    for (; j + 1 < end; j += 2) {
        int u0 = csr[j], u1 = csr[j + 1];
        float4 m0 = tsv[u0 * 16 + q];
        float4 m1 = tsv[u1 * 16 + q];
        acc.x += m0.x; acc.y += m0.y; acc.z += m0.z; acc.w += m0.w;
        acc.x += m1.x; acc.y += m1.y; acc.z += m1.z; acc.w += m1.w;
    }
    if (j < end) {
        int u = csr[j];
        float4 m = tsv[u * 16 + q];
        acc.x += m.x; acc.y += m.y; acc.z += m.z; acc.w += m.w;
    }
    float dv = dis[v];
    float4 bb = ((const float4*)b)[q];
    float4 r;
    r.x = fmaxf(acc.x * dv + bb.x, 0.0f);
    r.y = fmaxf(acc.y * dv + bb.y, 0.0f);
    r.z = fmaxf(acc.z * dv + bb.z, 0.0f);
    r.w = fmaxf(acc.w * dv + bb.w, 0.0f);
    ((float4*)h)[v * 16 + q] = r;
}

// ---------------- gather, 40 features: 10 threads/node, float4 each ----------------
__global__ __launch_bounds__(256) void gather40_kernel(const int* __restrict__ rowptr,
                                                       const int* __restrict__ csr,
                                                       const float* __restrict__ ts,
                                                       const float* __restrict__ dis,
                                                       const float* __restrict__ b,
                                                       float* __restrict__ out, int n) {
    int tid = blockIdx.x * 256 + threadIdx.x;
    int v = tid / 10, q = tid - v * 10;
    if (v >= n) return;
    const float4* tsv = (const float4*)ts;
    int beg = rowptr[v], end = rowptr[v + 1];
    float4 acc = tsv[v * 10 + q];
    int j = beg;
    for (; j + 1 < end; j += 2) {
        int u0 = csr[j], u1 = csr[j + 1];
        float4 m0 = tsv[u0 * 10 + q];
        float4 m1 = tsv[u1 * 10 + q];
        acc.x += m0.x; acc.y += m0.y; acc.z += m0.z; acc.w += m0.w;
        acc.x += m1.x; acc.y += m1.y; acc.z += m1.z; acc.w += m1.w;
    }
    if (j < end) {
        int u = csr[j];
        float4 m = tsv[u * 10 + q];
        acc.x += m.x; acc.y += m.y; acc.z += m.z; acc.w += m.w;
    }
    float dv = dis[v];
    float4 bb = ((const float4*)b)[q];
    float4 r;
    r.x = acc.x * dv + bb.x;
    r.y = acc.y * dv + bb.y;
    r.z = acc.z * dv + bb.z;
    r.w = acc.w * dv + bb.w;
    ((float4*)out)[v * 10 + q] = r;
}

// ---------------- log_softmax over 40, in place ----------------
__global__ __launch_bounds__(256) void logsoftmax_kernel(float* __restrict__ out, int n) {
    int v = blockIdx.x * 256 + threadIdx.x;
    if (v >= n) return;
    float4* rowp = (float4*)(out + (long long)v * OUT_DIM);
    float4 vals[10];
    float m = -1e30f;
#pragma unroll
    for (int i = 0; i < 10; ++i) {
        vals[i] = rowp[i];
        m = fmaxf(m, fmaxf(fmaxf(vals[i].x, vals[i].y), fmaxf(vals[i].z, vals[i].w)));
    }
    float s = 0.0f;
#pragma unroll
    for (int i = 0; i < 10; ++i) {
        s += expf(vals[i].x - m) + expf(vals[i].y - m) +
             expf(vals[i].z - m) + expf(vals[i].w - m);
    }
    float c = m + logf(s);
#pragma unroll
    for (int i = 0; i < 10; ++i) {
        vals[i].x -= c; vals[i].y -= c; vals[i].z -= c; vals[i].w -= c;
        rowp[i] = vals[i];
    }
}

extern "C" void kernel_launch(void* const* d_in, const int* in_sizes, int n_in,
                              void* d_out, int out_size, void* d_ws, size_t ws_size,
                              hipStream_t stream) {
    const float* x  = (const float*)d_in[0];
    const int*   ei = (const int*)d_in[1];
    const float* W1 = (const float*)d_in[2];
    const float* b1 = (const float*)d_in[3];
    const float* W2 = (const float*)d_in[4];
    const float* b2 = (const float*)d_in[5];
    float* out = (float*)d_out;

    const int* src = ei;             // edge_index[0]
    const int* dst = ei + N_EDGES;   // edge_index[1]

    // workspace layout (bytes):
    char* ws = (char*)d_ws;
    int*   deg     = (int*)ws;                          // 400 KB
    int*   rowptr  = (int*)(ws + 512 * 1024);           // 400 KB (+1 entry)
    int*   cursor  = (int*)(ws + 1024 * 1024);          // 400 KB (per-node, pass B)
    float* dis     = (float*)(ws + 1536 * 1024);        // 400 KB
    int*   bsum    = (int*)(ws + 1960 * 1024);          // 98 ints
    int*   cursorA = (int*)(ws + 1964 * 1024);          // 196 ints (per-bucket)
    int*   csr     = (int*)(ws + 2048 * 1024);          // 6.4 MB
    char*  ws2     = ws + 2048 * 1024 + 6553600;
    float* ts1     = (float*)ws2;                       // 25.6 MB
    float* h       = (float*)(ws2 + 26214400);          // 25.6 MB
    int2*  buk     = (int2*)h;                          // 12.8 MB, dead before gather64
    float* ts2     = ts1;                               // ts1 dead after gather64

    hipMemsetAsync(deg, 0, N_NODES * sizeof(int), stream);

    // CSR build (dst-grouped) via two-pass bucket partition
    deg_kernel<<<(N_EDGES + 255) / 256, 256, 0, stream>>>(dst, deg, N_EDGES);
    dis_kernel<<<(N_NODES + 255) / 256, 256, 0, stream>>>(deg, dis, N_NODES);
    scan1_kernel<<<SCAN_NB, 256, 0, stream>>>(deg, bsum, N_NODES);
    scan2_kernel<<<1, 128, 0, stream>>>(bsum, SCAN_NB);
    scan3_kernel<<<SCAN_NB, 256, 0, stream>>>(deg, bsum, rowptr, cursor, N_NODES);
    bukinit_kernel<<<1, 256, 0, stream>>>(rowptr, cursorA);
    partA_kernel<<<(N_EDGES + PART_CHUNK - 1) / PART_CHUNK, 256, 0, stream>>>(src, dst, cursorA,
                                                                              buk, N_EDGES);
    partB_kernel<<<(N_EDGES + 255) / 256, 256, 0, stream>>>(buk, cursor, csr, N_EDGES);

    // layer 1: ts1 = dis * (X @ W1); h = relu(dis*(sum+self) + b1)
    gemm_kernel<128, 64, 32, 16, 4, 2>
        <<<(N_NODES + 31) / 32, 256, 0, stream>>>(x, W1, dis, ts1, N_NODES);
    gather64_kernel<<<(N_NODES * 16 + 255) / 256, 256, 0, stream>>>(rowptr, csr, ts1, dis, b1,
                                                                    h, N_NODES);

    // layer 2: ts2 = dis * (h @ W2); out = dis*(sum+self) + b2 -> log_softmax
    gemm_kernel<64, 40, 64, 8, 5, 2>
        <<<(N_NODES + 63) / 64, 256, 0, stream>>>(h, W2, dis, ts2, N_NODES);
    gather40_kernel<<<(N_NODES * 10 + 255) / 256, 256, 0, stream>>>(rowptr, csr, ts2, dis, b2,
                                                                    out, N_NODES);
    logsoftmax_kernel<<<(N_NODES + 255) / 256, 256, 0, stream>>>(out, N_NODES);
}

// Round 6
// 256.621 us; speedup vs baseline: 3.2412x; 1.3725x over previous
//
#include <hip/hip_runtime.h>

#define N_NODES 100000
#define N_EDGES 1600000
#define IN_DIM  128
#define HID_DIM 64
#define OUT_DIM 40

#define SCAN_CHUNK 1024
#define SCAN_NB ((N_NODES + SCAN_CHUNK - 1) / SCAN_CHUNK)   // 98

#define BUK_SHIFT 9
#define NBUK ((N_NODES + (1 << BUK_SHIFT) - 1) >> BUK_SHIFT)  // 196
#define PART_CHUNK 4096
#define PART_EPT 16     // PART_CHUNK / 256

typedef unsigned short ushort;
typedef unsigned int uint;
typedef __attribute__((ext_vector_type(8))) short bf16x8;
typedef __attribute__((ext_vector_type(4))) float f32x4;

// float -> bf16 bits, round-to-nearest-even
__device__ __forceinline__ ushort f2bf(float x) {
    uint u = __float_as_uint(x);
    uint r = ((u >> 16) & 1u) + 0x7fffu;
    return (ushort)((u + r) >> 16);
}

// ---------------- in-degree histogram ----------------
__global__ __launch_bounds__(256) void deg_kernel(const int* __restrict__ dst,
                                                  int* __restrict__ deg, int E) {
    int i = blockIdx.x * 256 + threadIdx.x;
    if (i < E) atomicAdd(&deg[dst[i]], 1);
}

__global__ __launch_bounds__(256) void dis_kernel(const int* __restrict__ deg,
                                                  float* __restrict__ dis, int n) {
    int i = blockIdx.x * 256 + threadIdx.x;
    if (i < n) dis[i] = rsqrtf((float)deg[i] + 1.0f);
}

// ---------------- hierarchical scan: deg -> rowptr/cursor ----------------
__global__ __launch_bounds__(256) void scan1_kernel(const int* __restrict__ deg,
                                                    int* __restrict__ bsum, int n) {
    __shared__ int red[256];
    int t = threadIdx.x;
    int base = blockIdx.x * SCAN_CHUNK + t * 4;
    int s = 0;
#pragma unroll
    for (int i = 0; i < 4; ++i) { int idx = base + i; if (idx < n) s += deg[idx]; }
    red[t] = s;
    __syncthreads();
    for (int off = 128; off > 0; off >>= 1) {
        if (t < off) red[t] += red[t + off];
        __syncthreads();
    }
    if (t == 0) bsum[blockIdx.x] = red[0];
}

__global__ __launch_bounds__(128) void scan2_kernel(int* __restrict__ bsum, int nb) {
    __shared__ int sh[128];
    int t = threadIdx.x;
    sh[t] = (t < nb) ? bsum[t] : 0;
    __syncthreads();
    for (int off = 1; off < 128; off <<= 1) {
        int val = (t >= off) ? sh[t - off] : 0;
        __syncthreads();
        sh[t] += val;
        __syncthreads();
    }
    if (t < nb) bsum[t] = (t > 0) ? sh[t - 1] : 0;
}

__global__ __launch_bounds__(256) void scan3_kernel(const int* __restrict__ deg,
                                                    const int* __restrict__ bsum,
                                                    int* __restrict__ rowptr,
                                                    int* __restrict__ cursor, int n) {
    __shared__ int sh[256];
    int t = threadIdx.x;
    int base = blockIdx.x * SCAN_CHUNK + t * 4;
    int d[4];
    int s = 0;
#pragma unroll
    for (int i = 0; i < 4; ++i) {
        int idx = base + i;
        d[i] = (idx < n) ? deg[idx] : 0;
        s += d[i];
    }
    sh[t] = s;
    __syncthreads();
    for (int off = 1; off < 256; off <<= 1) {
        int val = (t >= off) ? sh[t - off] : 0;
        __syncthreads();
        sh[t] += val;
        __syncthreads();
    }
    int run = bsum[blockIdx.x] + ((t > 0) ? sh[t - 1] : 0);
#pragma unroll
    for (int i = 0; i < 4; ++i) {
        int idx = base + i;
        if (idx < n) {
            rowptr[idx] = run;
            cursor[idx] = run;
            run += d[i];
        }
    }
    if (blockIdx.x == 0 && t == 0) rowptr[n] = N_EDGES;
}

__global__ __launch_bounds__(256) void bukinit_kernel(const int* __restrict__ rowptr,
                                                      int* __restrict__ cursorA) {
    int b = blockIdx.x * 256 + threadIdx.x;
    if (b < NBUK) cursorA[b] = rowptr[b << BUK_SHIFT];
}

// ---------------- pass A: partition edges into dst-buckets ----------------
__global__ __launch_bounds__(256) void partA_kernel(const int* __restrict__ src,
                                                    const int* __restrict__ dst,
                                                    int* __restrict__ cursorA,
                                                    int2* __restrict__ buk, int E) {
    __shared__ int hist[NBUK];
    __shared__ int base[NBUK];
    const int t = threadIdx.x;
    const int e0 = blockIdx.x * PART_CHUNK;
    for (int i = t; i < NBUK; i += 256) hist[i] = 0;
    __syncthreads();
    int mys[PART_EPT], myd[PART_EPT];
#pragma unroll
    for (int i = 0; i < PART_EPT; ++i) {
        int e = e0 + t + i * 256;
        if (e < E) {
            mys[i] = src[e];
            myd[i] = dst[e];
            atomicAdd(&hist[myd[i] >> BUK_SHIFT], 1);
        } else {
            myd[i] = -1;
        }
    }
    __syncthreads();
    for (int i = t; i < NBUK; i += 256)
        base[i] = (hist[i] > 0) ? atomicAdd(&cursorA[i], hist[i]) : 0;
    __syncthreads();
    for (int i = t; i < NBUK; i += 256) hist[i] = 0;
    __syncthreads();
#pragma unroll
    for (int i = 0; i < PART_EPT; ++i) {
        if (myd[i] >= 0) {
            int b = myd[i] >> BUK_SHIFT;
            int pos = base[b] + atomicAdd(&hist[b], 1);
            buk[pos] = make_int2(mys[i], myd[i]);
        }
    }
}

// ---------------- pass B: bucket-local scatter into csr ----------------
__global__ __launch_bounds__(256) void partB_kernel(const int2* __restrict__ buk,
                                                    int* __restrict__ cursor,
                                                    int* __restrict__ csr, int E) {
    int i = blockIdx.x * 256 + threadIdx.x;
    if (i < E) {
        int2 e = buk[i];
        int pos = atomicAdd(&cursor[e.y], 1);
        csr[pos] = e.x;
    }
}

// ---------------- W pre-pack into B-fragment order ----------------
// Wb layout: frag (ks, ct) at ((ks*NCT + ct)*64 + lane)*8 ushorts
// value j: W[(ks*32 + (lane>>4)*8 + j) * ldw + ct*16 + (lane&15)]
__global__ __launch_bounds__(256) void packW1_kernel(const float* __restrict__ W,
                                                     ushort* __restrict__ Wb) {
    int t = blockIdx.x * 256 + threadIdx.x;   // 4 ks * 4 ct * 64 = 1024
    int lane = t & 63;
    int ct = (t >> 6) & 3;
    int ks = t >> 8;
    int c = ct * 16 + (lane & 15);
    int kb = ks * 32 + ((lane >> 4) << 3);
#pragma unroll
    for (int j = 0; j < 8; ++j)
        Wb[t * 8 + j] = f2bf(W[(kb + j) * HID_DIM + c]);
}

__global__ __launch_bounds__(256) void packW2_kernel(const float* __restrict__ W,
                                                     ushort* __restrict__ Wb) {
    int t = blockIdx.x * 256 + threadIdx.x;   // 2 ks * 3 ct * 64 = 384
    if (t >= 384) return;
    int lane = t & 63;
    int f = t >> 6;          // 0..5
    int ks = f / 3, ct = f % 3;
    int c = ct * 16 + (lane & 15);
    int kb = ks * 32 + ((lane >> 4) << 3);
#pragma unroll
    for (int j = 0; j < 8; ++j)
        Wb[t * 8 + j] = (c < OUT_DIM) ? f2bf(W[(kb + j) * OUT_DIM + c]) : 0;
}

// ---------------- MFMA GEMM1: ts1(bf16[M][64]) = dis * (X(f32[M][128]) @ W1) ----------------
__global__ __launch_bounds__(256) void mgemm1_kernel(const float* __restrict__ X,
                                                     const ushort* __restrict__ Wb,
                                                     const float* __restrict__ dis,
                                                     ushort* __restrict__ Y, int M) {
    const int wave = threadIdx.x >> 6;
    const int lane = threadIdx.x & 63;
    const int r0 = blockIdx.x * 128 + wave * 32;
    const int la = lane & 15, lb = lane >> 4;

    f32x4 acc[2][4];
#pragma unroll
    for (int i = 0; i < 2; ++i)
#pragma unroll
        for (int j = 0; j < 4; ++j)
#pragma unroll
            for (int r = 0; r < 4; ++r) acc[i][j][r] = 0.0f;

    int ra0 = r0 + la;       if (ra0 >= M) ra0 = M - 1;
    int ra1 = r0 + 16 + la;  if (ra1 >= M) ra1 = M - 1;
    const float* xp0 = X + (long long)ra0 * IN_DIM + lb * 8;
    const float* xp1 = X + (long long)ra1 * IN_DIM + lb * 8;
    const bf16x8* wb = (const bf16x8*)Wb;

#pragma unroll
    for (int ks = 0; ks < 4; ++ks) {
        float4 x00 = *(const float4*)(xp0 + ks * 32);
        float4 x01 = *(const float4*)(xp0 + ks * 32 + 4);
        float4 x10 = *(const float4*)(xp1 + ks * 32);
        float4 x11 = *(const float4*)(xp1 + ks * 32 + 4);
        bf16x8 a0, a1;
        a0[0] = (short)f2bf(x00.x); a0[1] = (short)f2bf(x00.y);
        a0[2] = (short)f2bf(x00.z); a0[3] = (short)f2bf(x00.w);
        a0[4] = (short)f2bf(x01.x); a0[5] = (short)f2bf(x01.y);
        a0[6] = (short)f2bf(x01.z); a0[7] = (short)f2bf(x01.w);
        a1[0] = (short)f2bf(x10.x); a1[1] = (short)f2bf(x10.y);
        a1[2] = (short)f2bf(x10.z); a1[3] = (short)f2bf(x10.w);
        a1[4] = (short)f2bf(x11.x); a1[5] = (short)f2bf(x11.y);
        a1[6] = (short)f2bf(x11.z); a1[7] = (short)f2bf(x11.w);
#pragma unroll
        for (int ct = 0; ct < 4; ++ct) {
            bf16x8 b = wb[(ks * 4 + ct) * 64 + lane];
            acc[0][ct] = __builtin_amdgcn_mfma_f32_16x16x32_bf16(a0, b, acc[0][ct], 0, 0, 0);
            acc[1][ct] = __builtin_amdgcn_mfma_f32_16x16x32_bf16(a1, b, acc[1][ct], 0, 0, 0);
        }
    }

#pragma unroll
    for (int rt = 0; rt < 2; ++rt)
#pragma unroll
        for (int r = 0; r < 4; ++r) {
            int row = r0 + rt * 16 + lb * 4 + r;
            if (row < M) {
                float dv = dis[row];
#pragma unroll
                for (int ct = 0; ct < 4; ++ct)
                    Y[(long long)row * HID_DIM + ct * 16 + la] = f2bf(acc[rt][ct][r] * dv);
            }
        }
}

// ---------------- MFMA GEMM2: ts2(bf16[M][48]) = dis * (H(bf16[M][64]) @ W2) ----------------
__global__ __launch_bounds__(256) void mgemm2_kernel(const ushort* __restrict__ H,
                                                     const ushort* __restrict__ Wb,
                                                     const float* __restrict__ dis,
                                                     ushort* __restrict__ Y, int M) {
    const int wave = threadIdx.x >> 6;
    const int lane = threadIdx.x & 63;
    const int r0 = blockIdx.x * 128 + wave * 32;
    const int la = lane & 15, lb = lane >> 4;

    f32x4 acc[2][3];
#pragma unroll
    for (int i = 0; i < 2; ++i)
#pragma unroll
        for (int j = 0; j < 3; ++j)
#pragma unroll
            for (int r = 0; r < 4; ++r) acc[i][j][r] = 0.0f;

    int ra0 = r0 + la;       if (ra0 >= M) ra0 = M - 1;
    int ra1 = r0 + 16 + la;  if (ra1 >= M) ra1 = M - 1;
    const ushort* hp0 = H + (long long)ra0 * HID_DIM + lb * 8;
    const ushort* hp1 = H + (long long)ra1 * HID_DIM + lb * 8;
    const bf16x8* wb = (const bf16x8*)Wb;

#pragma unroll
    for (int ks = 0; ks < 2; ++ks) {
        bf16x8 a0 = *(const bf16x8*)(hp0 + ks * 32);
        bf16x8 a1 = *(const bf16x8*)(hp1 + ks * 32);
#pragma unroll
        for (int ct = 0; ct < 3; ++ct) {
            bf16x8 b = wb[(ks * 3 + ct) * 64 + lane];
            acc[0][ct] = __builtin_amdgcn_mfma_f32_16x16x32_bf16(a0, b, acc[0][ct], 0, 0, 0);
            acc[1][ct] = __builtin_amdgcn_mfma_f32_16x16x32_bf16(a1, b, acc[1][ct], 0, 0, 0);
        }
    }

#pragma unroll
    for (int rt = 0; rt < 2; ++rt)
#pragma unroll
        for (int r = 0; r < 4; ++r) {
            int row = r0 + rt * 16 + lb * 4 + r;
            if (row < M) {
                float dv = dis[row];
#pragma unroll
                for (int ct = 0; ct < 3; ++ct)
                    Y[(long long)row * 48 + ct * 16 + la] = f2bf(acc[rt][ct][r] * dv);
            }
        }
}

// ---------------- bf16 unpack-accumulate ----------------
__device__ __forceinline__ void add_bf8(float* acc, uint4 m) {
    acc[0] += __uint_as_float(m.x << 16);
    acc[1] += __uint_as_float(m.x & 0xffff0000u);
    acc[2] += __uint_as_float(m.y << 16);
    acc[3] += __uint_as_float(m.y & 0xffff0000u);
    acc[4] += __uint_as_float(m.z << 16);
    acc[5] += __uint_as_float(m.z & 0xffff0000u);
    acc[6] += __uint_as_float(m.w << 16);
    acc[7] += __uint_as_float(m.w & 0xffff0000u);
}

// ---------------- gather 64 feats (bf16): 8 threads/node, 8 feats each ----------------
// h[v] = relu(dis[v]*(sum_{u in N(v)} ts[u] + ts[v]) + b)  -> bf16
__global__ __launch_bounds__(256) void gather64_kernel(const int* __restrict__ rowptr,
                                                       const int* __restrict__ csr,
                                                       const ushort* __restrict__ ts,
                                                       const float* __restrict__ dis,
                                                       const float* __restrict__ b,
                                                       ushort* __restrict__ h, int n) {
    int tid = blockIdx.x * 256 + threadIdx.x;
    int v = tid >> 3, q = tid & 7;
    if (v >= n) return;
    const uint4* tsv = (const uint4*)ts;
    int beg = rowptr[v], end = rowptr[v + 1];
    float acc[8];
    {
        uint4 m = tsv[v * 8 + q];
        acc[0] = __uint_as_float(m.x << 16);
        acc[1] = __uint_as_float(m.x & 0xffff0000u);
        acc[2] = __uint_as_float(m.y << 16);
        acc[3] = __uint_as_float(m.y & 0xffff0000u);
        acc[4] = __uint_as_float(m.z << 16);
        acc[5] = __uint_as_float(m.z & 0xffff0000u);
        acc[6] = __uint_as_float(m.w << 16);
        acc[7] = __uint_as_float(m.w & 0xffff0000u);
    }
    int j = beg;
    for (; j + 1 < end; j += 2) {
        int u0 = csr[j], u1 = csr[j + 1];
        uint4 m0 = tsv[u0 * 8 + q];
        uint4 m1 = tsv[u1 * 8 + q];
        add_bf8(acc, m0);
        add_bf8(acc, m1);
    }
    if (j < end) add_bf8(acc, tsv[csr[j] * 8 + q]);

    float dv = dis[v];
    float4 b0 = ((const float4*)b)[q * 2];
    float4 b1 = ((const float4*)b)[q * 2 + 1];
    float r0 = fmaxf(acc[0] * dv + b0.x, 0.0f);
    float r1 = fmaxf(acc[1] * dv + b0.y, 0.0f);
    float r2 = fmaxf(acc[2] * dv + b0.z, 0.0f);
    float r3 = fmaxf(acc[3] * dv + b0.w, 0.0f);
    float r4 = fmaxf(acc[4] * dv + b1.x, 0.0f);
    float r5 = fmaxf(acc[5] * dv + b1.y, 0.0f);
    float r6 = fmaxf(acc[6] * dv + b1.z, 0.0f);
    float r7 = fmaxf(acc[7] * dv + b1.w, 0.0f);
    uint4 o;
    o.x = ((uint)f2bf(r1) << 16) | f2bf(r0);
    o.y = ((uint)f2bf(r3) << 16) | f2bf(r2);
    o.z = ((uint)f2bf(r5) << 16) | f2bf(r4);
    o.w = ((uint)f2bf(r7) << 16) | f2bf(r6);
    ((uint4*)h)[v * 8 + q] = o;
}

// ---------------- gather 40 feats (bf16 in, f32 out): 5 threads/node ----------------
// out[v] = dis[v]*(sum ts[u] + ts[v]) + b   (ts stride 48)
__global__ __launch_bounds__(256) void gather40_kernel(const int* __restrict__ rowptr,
                                                       const int* __restrict__ csr,
                                                       const ushort* __restrict__ ts,
                                                       const float* __restrict__ dis,
                                                       const float* __restrict__ b,
                                                       float* __restrict__ out, int n) {
    int tid = blockIdx.x * 256 + threadIdx.x;
    int v = tid / 5, q = tid - v * 5;
    if (v >= n) return;
    const uint4* tsv = (const uint4*)ts;   // row stride 48 bf16 = 6 uint4
    int beg = rowptr[v], end = rowptr[v + 1];
    float acc[8];
    {
        uint4 m = tsv[v * 6 + q];
        acc[0] = __uint_as_float(m.x << 16);
        acc[1] = __uint_as_float(m.x & 0xffff0000u);
        acc[2] = __uint_as_float(m.y << 16);
        acc[3] = __uint_as_float(m.y & 0xffff0000u);
        acc[4] = __uint_as_float(m.z << 16);
        acc[5] = __uint_as_float(m.z & 0xffff0000u);
        acc[6] = __uint_as_float(m.w << 16);
        acc[7] = __uint_as_float(m.w & 0xffff0000u);
    }
    int j = beg;
    for (; j + 1 < end; j += 2) {
        int u0 = csr[j], u1 = csr[j + 1];
        uint4 m0 = tsv[u0 * 6 + q];
        uint4 m1 = tsv[u1 * 6 + q];
        add_bf8(acc, m0);
        add_bf8(acc, m1);
    }
    if (j < end) add_bf8(acc, tsv[csr[j] * 6 + q]);

    float dv = dis[v];
    float4 b0 = ((const float4*)b)[q * 2];
    float4 b1 = ((const float4*)b)[q * 2 + 1];
    float4 o0, o1;
    o0.x = acc[0] * dv + b0.x;
    o0.y = acc[1] * dv + b0.y;
    o0.z = acc[2] * dv + b0.z;
    o0.w = acc[3] * dv + b0.w;
    o1.x = acc[4] * dv + b1.x;
    o1.y = acc[5] * dv + b1.y;
    o1.z = acc[6] * dv + b1.z;
    o1.w = acc[7] * dv + b1.w;
    ((float4*)out)[v * 10 + q * 2]     = o0;
    ((float4*)out)[v * 10 + q * 2 + 1] = o1;
}

// ---------------- log_softmax over 40, in place ----------------
__global__ __launch_bounds__(256) void logsoftmax_kernel(float* __restrict__ out, int n) {
    int v = blockIdx.x * 256 + threadIdx.x;
    if (v >= n) return;
    float4* rowp = (float4*)(out + (long long)v * OUT_DIM);
    float4 vals[10];
    float m = -1e30f;
#pragma unroll
    for (int i = 0; i < 10; ++i) {
        vals[i] = rowp[i];
        m = fmaxf(m, fmaxf(fmaxf(vals[i].x, vals[i].y), fmaxf(vals[i].z, vals[i].w)));
    }
    float s = 0.0f;
#pragma unroll
    for (int i = 0; i < 10; ++i) {
        s += expf(vals[i].x - m) + expf(vals[i].y - m) +
             expf(vals[i].z - m) + expf(vals[i].w - m);
    }
    float c = m + logf(s);
#pragma unroll
    for (int i = 0; i < 10; ++i) {
        vals[i].x -= c; vals[i].y -= c; vals[i].z -= c; vals[i].w -= c;
        rowp[i] = vals[i];
    }
}

extern "C" void kernel_launch(void* const* d_in, const int* in_sizes, int n_in,
                              void* d_out, int out_size, void* d_ws, size_t ws_size,
                              hipStream_t stream) {
    const float* x  = (const float*)d_in[0];
    const int*   ei = (const int*)d_in[1];
    const float* W1 = (const float*)d_in[2];
    const float* b1 = (const float*)d_in[3];
    const float* W2 = (const float*)d_in[4];
    const float* b2 = (const float*)d_in[5];
    float* out = (float*)d_out;

    const int* src = ei;
    const int* dst = ei + N_EDGES;

    // workspace layout (bytes) — NOTE: dis spans [1536KB, 1926.6KB); keep
    // bsum/cursorA/Wb1/Wb2 ABOVE that and below csr at 2048KB.
    char* ws = (char*)d_ws;
    int*    deg     = (int*)ws;                         // [0, 390.6KB)
    int*    rowptr  = (int*)(ws + (512 << 10));         // [512KB, 902.6KB)+4
    int*    cursor  = (int*)(ws + (1024 << 10));        // [1024KB, 1414.6KB)
    float*  dis     = (float*)(ws + (1536 << 10));      // [1536KB, 1926.6KB)
    int*    bsum    = (int*)(ws + (1928 << 10));        // 392 B
    int*    cursorA = (int*)(ws + (1932 << 10));        // 784 B
    ushort* Wb1     = (ushort*)(ws + (1936 << 10));     // 16 KB -> ends 1952KB
    ushort* Wb2     = (ushort*)(ws + (1956 << 10));     // 6 KB  -> ends 1962KB
    int*    csr     = (int*)(ws + (2048 << 10));        // 6.4 MB
    char*   p       = ws + (2048 << 10) + 6553600;
    ushort* ts1     = (ushort*)p;                       // 12.8 MB (bf16 [M][64])
    int2*   buk     = (int2*)p;                         // aliases ts1 (dead before mgemm1)
    ushort* h       = (ushort*)(p + 12800000);          // 12.8 MB (bf16 [M][64])
    ushort* ts2     = (ushort*)(p + 25600000);          // 9.6 MB (bf16 [M][48])

    hipMemsetAsync(deg, 0, N_NODES * sizeof(int), stream);

    // CSR build (dst-grouped) via two-pass bucket partition
    deg_kernel<<<(N_EDGES + 255) / 256, 256, 0, stream>>>(dst, deg, N_EDGES);
    dis_kernel<<<(N_NODES + 255) / 256, 256, 0, stream>>>(deg, dis, N_NODES);
    scan1_kernel<<<SCAN_NB, 256, 0, stream>>>(deg, bsum, N_NODES);
    scan2_kernel<<<1, 128, 0, stream>>>(bsum, SCAN_NB);
    scan3_kernel<<<SCAN_NB, 256, 0, stream>>>(deg, bsum, rowptr, cursor, N_NODES);
    bukinit_kernel<<<1, 256, 0, stream>>>(rowptr, cursorA);
    partA_kernel<<<(N_EDGES + PART_CHUNK - 1) / PART_CHUNK, 256, 0, stream>>>(src, dst, cursorA,
                                                                              buk, N_EDGES);
    partB_kernel<<<(N_EDGES + 255) / 256, 256, 0, stream>>>(buk, cursor, csr, N_EDGES);

    // weight pre-pack (B-fragment order)
    packW1_kernel<<<4, 256, 0, stream>>>(W1, Wb1);
    packW2_kernel<<<2, 256, 0, stream>>>(W2, Wb2);

    // layer 1
    mgemm1_kernel<<<(N_NODES + 127) / 128, 256, 0, stream>>>(x, Wb1, dis, ts1, N_NODES);
    gather64_kernel<<<(N_NODES * 8 + 255) / 256, 256, 0, stream>>>(rowptr, csr, ts1, dis, b1,
                                                                   h, N_NODES);

    // layer 2
    mgemm2_kernel<<<(N_NODES + 127) / 128, 256, 0, stream>>>(h, Wb2, dis, ts2, N_NODES);
    gather40_kernel<<<(N_NODES * 5 + 255) / 256, 256, 0, stream>>>(rowptr, csr, ts2, dis, b2,
                                                                   out, N_NODES);
    logsoftmax_kernel<<<(N_NODES + 255) / 256, 256, 0, stream>>>(out, N_NODES);
}

// Round 7
// 170.324 us; speedup vs baseline: 4.8833x; 1.5067x over previous
//
#include <hip/hip_runtime.h>

#define N_NODES 100000
#define N_EDGES 1600000
#define IN_DIM  128
#define HID_DIM 64
#define OUT_DIM 40

#define BUK_SHIFT 9
#define NBUK ((N_NODES + (1 << BUK_SHIFT) - 1) >> BUK_SHIFT)  // 196
#define PART_CHUNK 4096
#define PART_EPT 16     // PART_CHUNK / 256

typedef unsigned short ushort;
typedef unsigned int uint;
typedef __attribute__((ext_vector_type(8))) short bf16x8;
typedef __attribute__((ext_vector_type(4))) float f32x4;

// float -> bf16 bits, round-to-nearest-even
__device__ __forceinline__ ushort f2bf(float x) {
    uint u = __float_as_uint(x);
    uint r = ((u >> 16) & 1u) + 0x7fffu;
    return (ushort)((u + r) >> 16);
}

// ---------------- bucket histogram (196 counters, LDS-staged) ----------------
__global__ __launch_bounds__(256) void bukhist_kernel(const int* __restrict__ dst,
                                                      int* __restrict__ bukcnt, int E) {
    __shared__ int h[NBUK];
    const int t = threadIdx.x;
    for (int i = t; i < NBUK; i += 256) h[i] = 0;
    __syncthreads();
    const int e0 = blockIdx.x * PART_CHUNK;
#pragma unroll
    for (int i = 0; i < PART_EPT; ++i) {
        int e = e0 + t + i * 256;
        if (e < E) atomicAdd(&h[dst[e] >> BUK_SHIFT], 1);
    }
    __syncthreads();
    for (int i = t; i < NBUK; i += 256)
        if (h[i]) atomicAdd(&bukcnt[i], h[i]);
}

// ---------------- single-block scan of bucket counts -> bbase, cursorA ----------------
__global__ __launch_bounds__(256) void scanB_kernel(const int* __restrict__ bukcnt,
                                                    int* __restrict__ bbase,
                                                    int* __restrict__ cursorA,
                                                    int* __restrict__ rowptr) {
    __shared__ int sh[256];
    const int t = threadIdx.x;
    sh[t] = (t < NBUK) ? bukcnt[t] : 0;
    __syncthreads();
    for (int off = 1; off < 256; off <<= 1) {
        int v = (t >= off) ? sh[t - off] : 0;
        __syncthreads();
        sh[t] += v;
        __syncthreads();
    }
    if (t < NBUK) {
        int base = (t > 0) ? sh[t - 1] : 0;
        bbase[t] = base;
        cursorA[t] = base;
    }
    if (t == 0) { bbase[NBUK] = N_EDGES; rowptr[N_NODES] = N_EDGES; }
}

// ---------------- pass A: partition edges into dst-buckets ----------------
__global__ __launch_bounds__(256) void partA_kernel(const int* __restrict__ src,
                                                    const int* __restrict__ dst,
                                                    int* __restrict__ cursorA,
                                                    int2* __restrict__ buk, int E) {
    __shared__ int hist[NBUK];
    __shared__ int base[NBUK];
    const int t = threadIdx.x;
    const int e0 = blockIdx.x * PART_CHUNK;
    for (int i = t; i < NBUK; i += 256) hist[i] = 0;
    __syncthreads();
    int mys[PART_EPT], myd[PART_EPT];
#pragma unroll
    for (int i = 0; i < PART_EPT; ++i) {
        int e = e0 + t + i * 256;
        if (e < E) {
            mys[i] = src[e];
            myd[i] = dst[e];
            atomicAdd(&hist[myd[i] >> BUK_SHIFT], 1);
        } else {
            myd[i] = -1;
        }
    }
    __syncthreads();
    for (int i = t; i < NBUK; i += 256)
        base[i] = (hist[i] > 0) ? atomicAdd(&cursorA[i], hist[i]) : 0;
    __syncthreads();
    for (int i = t; i < NBUK; i += 256) hist[i] = 0;
    __syncthreads();
#pragma unroll
    for (int i = 0; i < PART_EPT; ++i) {
        if (myd[i] >= 0) {
            int b = myd[i] >> BUK_SHIFT;
            int pos = base[b] + atomicAdd(&hist[b], 1);
            buk[pos] = make_int2(mys[i], myd[i]);
        }
    }
}

// ---------------- per-bucket: node degrees + rowptr + dis + csr fill, all LDS ----------------
__global__ __launch_bounds__(512) void bucket_kernel(const int2* __restrict__ buk,
                                                     const int* __restrict__ bbase,
                                                     int* __restrict__ rowptr,
                                                     float* __restrict__ dis,
                                                     int* __restrict__ csr, int n) {
    __shared__ int cnt[512];
    __shared__ int pre[512];
    const int t = threadIdx.x;
    const int b = blockIdx.x;
    const int beg = bbase[b], end = bbase[b + 1];
    cnt[t] = 0;
    __syncthreads();
    for (int i = beg + t; i < end; i += 512)
        atomicAdd(&cnt[buk[i].y & 511], 1);
    __syncthreads();
    const int c = cnt[t];
    pre[t] = c;
    __syncthreads();
    for (int off = 1; off < 512; off <<= 1) {
        int v = (t >= off) ? pre[t - off] : 0;
        __syncthreads();
        pre[t] += v;
        __syncthreads();
    }
    const int ex = pre[t] - c;   // exclusive prefix within bucket
    const int v0 = (b << BUK_SHIFT) + t;
    if (v0 < n) {
        rowptr[v0] = beg + ex;
        dis[v0] = rsqrtf((float)c + 1.0f);
    }
    __syncthreads();
    cnt[t] = beg + ex;           // cursor (safe: each thread read only cnt[t] above)
    __syncthreads();
    for (int i = beg + t; i < end; i += 512) {
        int2 e = buk[i];
        int pos = atomicAdd(&cnt[e.y & 511], 1);
        csr[pos] = e.x;
    }
}

// ---------------- W pre-pack into B-fragment order ----------------
// Wb layout: frag (ks, ct) at ((ks*NCT + ct)*64 + lane)*8 ushorts
// value j: W[(ks*32 + (lane>>4)*8 + j) * ldw + ct*16 + (lane&15)]
__global__ __launch_bounds__(256) void packW1_kernel(const float* __restrict__ W,
                                                     ushort* __restrict__ Wb) {
    int t = blockIdx.x * 256 + threadIdx.x;   // 4 ks * 4 ct * 64 = 1024
    int lane = t & 63;
    int ct = (t >> 6) & 3;
    int ks = t >> 8;
    int c = ct * 16 + (lane & 15);
    int kb = ks * 32 + ((lane >> 4) << 3);
#pragma unroll
    for (int j = 0; j < 8; ++j)
        Wb[t * 8 + j] = f2bf(W[(kb + j) * HID_DIM + c]);
}

__global__ __launch_bounds__(256) void packW2_kernel(const float* __restrict__ W,
                                                     ushort* __restrict__ Wb) {
    int t = blockIdx.x * 256 + threadIdx.x;   // 2 ks * 3 ct * 64 = 384
    if (t >= 384) return;
    int lane = t & 63;
    int f = t >> 6;          // 0..5
    int ks = f / 3, ct = f % 3;
    int c = ct * 16 + (lane & 15);
    int kb = ks * 32 + ((lane >> 4) << 3);
#pragma unroll
    for (int j = 0; j < 8; ++j)
        Wb[t * 8 + j] = (c < OUT_DIM) ? f2bf(W[(kb + j) * OUT_DIM + c]) : 0;
}

// ---------------- MFMA GEMM1: ts1(bf16[M][64]) = dis * (X(f32[M][128]) @ W1) ----------------
__global__ __launch_bounds__(256) void mgemm1_kernel(const float* __restrict__ X,
                                                     const ushort* __restrict__ Wb,
                                                     const float* __restrict__ dis,
                                                     ushort* __restrict__ Y, int M) {
    const int wave = threadIdx.x >> 6;
    const int lane = threadIdx.x & 63;
    const int r0 = blockIdx.x * 128 + wave * 32;
    const int la = lane & 15, lb = lane >> 4;

    f32x4 acc[2][4];
#pragma unroll
    for (int i = 0; i < 2; ++i)
#pragma unroll
        for (int j = 0; j < 4; ++j)
#pragma unroll
            for (int r = 0; r < 4; ++r) acc[i][j][r] = 0.0f;

    int ra0 = r0 + la;       if (ra0 >= M) ra0 = M - 1;
    int ra1 = r0 + 16 + la;  if (ra1 >= M) ra1 = M - 1;
    const float* xp0 = X + (long long)ra0 * IN_DIM + lb * 8;
    const float* xp1 = X + (long long)ra1 * IN_DIM + lb * 8;
    const bf16x8* wb = (const bf16x8*)Wb;

#pragma unroll
    for (int ks = 0; ks < 4; ++ks) {
        float4 x00 = *(const float4*)(xp0 + ks * 32);
        float4 x01 = *(const float4*)(xp0 + ks * 32 + 4);
        float4 x10 = *(const float4*)(xp1 + ks * 32);
        float4 x11 = *(const float4*)(xp1 + ks * 32 + 4);
        bf16x8 a0, a1;
        a0[0] = (short)f2bf(x00.x); a0[1] = (short)f2bf(x00.y);
        a0[2] = (short)f2bf(x00.z); a0[3] = (short)f2bf(x00.w);
        a0[4] = (short)f2bf(x01.x); a0[5] = (short)f2bf(x01.y);
        a0[6] = (short)f2bf(x01.z); a0[7] = (short)f2bf(x01.w);
        a1[0] = (short)f2bf(x10.x); a1[1] = (short)f2bf(x10.y);
        a1[2] = (short)f2bf(x10.z); a1[3] = (short)f2bf(x10.w);
        a1[4] = (short)f2bf(x11.x); a1[5] = (short)f2bf(x11.y);
        a1[6] = (short)f2bf(x11.z); a1[7] = (short)f2bf(x11.w);
#pragma unroll
        for (int ct = 0; ct < 4; ++ct) {
            bf16x8 b = wb[(ks * 4 + ct) * 64 + lane];
            acc[0][ct] = __builtin_amdgcn_mfma_f32_16x16x32_bf16(a0, b, acc[0][ct], 0, 0, 0);
            acc[1][ct] = __builtin_amdgcn_mfma_f32_16x16x32_bf16(a1, b, acc[1][ct], 0, 0, 0);
        }
    }

#pragma unroll
    for (int rt = 0; rt < 2; ++rt)
#pragma unroll
        for (int r = 0; r < 4; ++r) {
            int row = r0 + rt * 16 + lb * 4 + r;
            if (row < M) {
                float dv = dis[row];
#pragma unroll
                for (int ct = 0; ct < 4; ++ct)
                    Y[(long long)row * HID_DIM + ct * 16 + la] = f2bf(acc[rt][ct][r] * dv);
            }
        }
}

// ---------------- MFMA GEMM2: ts2(bf16[M][48]) = dis * (H(bf16[M][64]) @ W2) ----------------
__global__ __launch_bounds__(256) void mgemm2_kernel(const ushort* __restrict__ H,
                                                     const ushort* __restrict__ Wb,
                                                     const float* __restrict__ dis,
                                                     ushort* __restrict__ Y, int M) {
    const int wave = threadIdx.x >> 6;
    const int lane = threadIdx.x & 63;
    const int r0 = blockIdx.x * 128 + wave * 32;
    const int la = lane & 15, lb = lane >> 4;

    f32x4 acc[2][3];
#pragma unroll
    for (int i = 0; i < 2; ++i)
#pragma unroll
        for (int j = 0; j < 3; ++j)
#pragma unroll
            for (int r = 0; r < 4; ++r) acc[i][j][r] = 0.0f;

    int ra0 = r0 + la;       if (ra0 >= M) ra0 = M - 1;
    int ra1 = r0 + 16 + la;  if (ra1 >= M) ra1 = M - 1;
    const ushort* hp0 = H + (long long)ra0 * HID_DIM + lb * 8;
    const ushort* hp1 = H + (long long)ra1 * HID_DIM + lb * 8;
    const bf16x8* wb = (const bf16x8*)Wb;

#pragma unroll
    for (int ks = 0; ks < 2; ++ks) {
        bf16x8 a0 = *(const bf16x8*)(hp0 + ks * 32);
        bf16x8 a1 = *(const bf16x8*)(hp1 + ks * 32);
#pragma unroll
        for (int ct = 0; ct < 3; ++ct) {
            bf16x8 b = wb[(ks * 3 + ct) * 64 + lane];
            acc[0][ct] = __builtin_amdgcn_mfma_f32_16x16x32_bf16(a0, b, acc[0][ct], 0, 0, 0);
            acc[1][ct] = __builtin_amdgcn_mfma_f32_16x16x32_bf16(a1, b, acc[1][ct], 0, 0, 0);
        }
    }

#pragma unroll
    for (int rt = 0; rt < 2; ++rt)
#pragma unroll
        for (int r = 0; r < 4; ++r) {
            int row = r0 + rt * 16 + lb * 4 + r;
            if (row < M) {
                float dv = dis[row];
#pragma unroll
                for (int ct = 0; ct < 3; ++ct)
                    Y[(long long)row * 48 + ct * 16 + la] = f2bf(acc[rt][ct][r] * dv);
            }
        }
}

// ---------------- bf16 unpack-accumulate ----------------
__device__ __forceinline__ void add_bf8(float* acc, uint4 m) {
    acc[0] += __uint_as_float(m.x << 16);
    acc[1] += __uint_as_float(m.x & 0xffff0000u);
    acc[2] += __uint_as_float(m.y << 16);
    acc[3] += __uint_as_float(m.y & 0xffff0000u);
    acc[4] += __uint_as_float(m.z << 16);
    acc[5] += __uint_as_float(m.z & 0xffff0000u);
    acc[6] += __uint_as_float(m.w << 16);
    acc[7] += __uint_as_float(m.w & 0xffff0000u);
}

// ---------------- gather 64 feats (bf16): 8 threads/node, 8 feats each ----------------
__global__ __launch_bounds__(256) void gather64_kernel(const int* __restrict__ rowptr,
                                                       const int* __restrict__ csr,
                                                       const ushort* __restrict__ ts,
                                                       const float* __restrict__ dis,
                                                       const float* __restrict__ b,
                                                       ushort* __restrict__ h, int n) {
    int tid = blockIdx.x * 256 + threadIdx.x;
    int v = tid >> 3, q = tid & 7;
    if (v >= n) return;
    const uint4* tsv = (const uint4*)ts;
    int beg = rowptr[v], end = rowptr[v + 1];
    float acc[8];
    {
        uint4 m = tsv[v * 8 + q];
        acc[0] = __uint_as_float(m.x << 16);
        acc[1] = __uint_as_float(m.x & 0xffff0000u);
        acc[2] = __uint_as_float(m.y << 16);
        acc[3] = __uint_as_float(m.y & 0xffff0000u);
        acc[4] = __uint_as_float(m.z << 16);
        acc[5] = __uint_as_float(m.z & 0xffff0000u);
        acc[6] = __uint_as_float(m.w << 16);
        acc[7] = __uint_as_float(m.w & 0xffff0000u);
    }
    int j = beg;
    for (; j + 1 < end; j += 2) {
        int u0 = csr[j], u1 = csr[j + 1];
        uint4 m0 = tsv[u0 * 8 + q];
        uint4 m1 = tsv[u1 * 8 + q];
        add_bf8(acc, m0);
        add_bf8(acc, m1);
    }
    if (j < end) add_bf8(acc, tsv[csr[j] * 8 + q]);

    float dv = dis[v];
    float4 b0 = ((const float4*)b)[q * 2];
    float4 b1 = ((const float4*)b)[q * 2 + 1];
    float r0 = fmaxf(acc[0] * dv + b0.x, 0.0f);
    float r1 = fmaxf(acc[1] * dv + b0.y, 0.0f);
    float r2 = fmaxf(acc[2] * dv + b0.z, 0.0f);
    float r3 = fmaxf(acc[3] * dv + b0.w, 0.0f);
    float r4 = fmaxf(acc[4] * dv + b1.x, 0.0f);
    float r5 = fmaxf(acc[5] * dv + b1.y, 0.0f);
    float r6 = fmaxf(acc[6] * dv + b1.z, 0.0f);
    float r7 = fmaxf(acc[7] * dv + b1.w, 0.0f);
    uint4 o;
    o.x = ((uint)f2bf(r1) << 16) | f2bf(r0);
    o.y = ((uint)f2bf(r3) << 16) | f2bf(r2);
    o.z = ((uint)f2bf(r5) << 16) | f2bf(r4);
    o.w = ((uint)f2bf(r7) << 16) | f2bf(r6);
    ((uint4*)h)[v * 8 + q] = o;
}

// ---------------- gather 40 feats (bf16 in, f32 out): 5 threads/node ----------------
__global__ __launch_bounds__(256) void gather40_kernel(const int* __restrict__ rowptr,
                                                       const int* __restrict__ csr,
                                                       const ushort* __restrict__ ts,
                                                       const float* __restrict__ dis,
                                                       const float* __restrict__ b,
                                                       float* __restrict__ out, int n) {
    int tid = blockIdx.x * 256 + threadIdx.x;
    int v = tid / 5, q = tid - v * 5;
    if (v >= n) return;
    const uint4* tsv = (const uint4*)ts;   // row stride 48 bf16 = 6 uint4
    int beg = rowptr[v], end = rowptr[v + 1];
    float acc[8];
    {
        uint4 m = tsv[v * 6 + q];
        acc[0] = __uint_as_float(m.x << 16);
        acc[1] = __uint_as_float(m.x & 0xffff0000u);
        acc[2] = __uint_as_float(m.y << 16);
        acc[3] = __uint_as_float(m.y & 0xffff0000u);
        acc[4] = __uint_as_float(m.z << 16);
        acc[5] = __uint_as_float(m.z & 0xffff0000u);
        acc[6] = __uint_as_float(m.w << 16);
        acc[7] = __uint_as_float(m.w & 0xffff0000u);
    }
    int j = beg;
    for (; j + 1 < end; j += 2) {
        int u0 = csr[j], u1 = csr[j + 1];
        uint4 m0 = tsv[u0 * 6 + q];
        uint4 m1 = tsv[u1 * 6 + q];
        add_bf8(acc, m0);
        add_bf8(acc, m1);
    }
    if (j < end) add_bf8(acc, tsv[csr[j] * 6 + q]);

    float dv = dis[v];
    float4 b0 = ((const float4*)b)[q * 2];
    float4 b1 = ((const float4*)b)[q * 2 + 1];
    float4 o0, o1;
    o0.x = acc[0] * dv + b0.x;
    o0.y = acc[1] * dv + b0.y;
    o0.z = acc[2] * dv + b0.z;
    o0.w = acc[3] * dv + b0.w;
    o1.x = acc[4] * dv + b1.x;
    o1.y = acc[5] * dv + b1.y;
    o1.z = acc[6] * dv + b1.z;
    o1.w = acc[7] * dv + b1.w;
    ((float4*)out)[v * 10 + q * 2]     = o0;
    ((float4*)out)[v * 10 + q * 2 + 1] = o1;
}

// ---------------- log_softmax over 40, in place ----------------
__global__ __launch_bounds__(256) void logsoftmax_kernel(float* __restrict__ out, int n) {
    int v = blockIdx.x * 256 + threadIdx.x;
    if (v >= n) return;
    float4* rowp = (float4*)(out + (long long)v * OUT_DIM);
    float4 vals[10];
    float m = -1e30f;
#pragma unroll
    for (int i = 0; i < 10; ++i) {
        vals[i] = rowp[i];
        m = fmaxf(m, fmaxf(fmaxf(vals[i].x, vals[i].y), fmaxf(vals[i].z, vals[i].w)));
    }
    float s = 0.0f;
#pragma unroll
    for (int i = 0; i < 10; ++i) {
        s += expf(vals[i].x - m) + expf(vals[i].y - m) +
             expf(vals[i].z - m) + expf(vals[i].w - m);
    }
    float c = m + logf(s);
#pragma unroll
    for (int i = 0; i < 10; ++i) {
        vals[i].x -= c; vals[i].y -= c; vals[i].z -= c; vals[i].w -= c;
        rowp[i] = vals[i];
    }
}

extern "C" void kernel_launch(void* const* d_in, const int* in_sizes, int n_in,
                              void* d_out, int out_size, void* d_ws, size_t ws_size,
                              hipStream_t stream) {
    const float* x  = (const float*)d_in[0];
    const int*   ei = (const int*)d_in[1];
    const float* W1 = (const float*)d_in[2];
    const float* b1 = (const float*)d_in[3];
    const float* W2 = (const float*)d_in[4];
    const float* b2 = (const float*)d_in[5];
    float* out = (float*)d_out;

    const int* src = ei;
    const int* dst = ei + N_EDGES;

    // workspace layout (bytes) — regions verified non-overlapping:
    char* ws = (char*)d_ws;
    int*    rowptr  = (int*)ws;                         // [0, 400,004)
    float*  dis     = (float*)(ws + (512 << 10));       // [512K, 512K+400,000)
    int*    bukcnt  = (int*)(ws + (1024 << 10));        // 784 B
    int*    bbase   = (int*)(ws + (1028 << 10));        // 788 B
    int*    cursorA = (int*)(ws + (1032 << 10));        // 784 B
    ushort* Wb1     = (ushort*)(ws + (1036 << 10));     // 16 KB -> 1052K
    ushort* Wb2     = (ushort*)(ws + (1056 << 10));     // 6 KB  -> 1062K
    int*    csr     = (int*)(ws + (2048 << 10));        // 6.4 MB -> ~8.3 MB
    char*   p       = ws + (9216 << 10);                // 9 MB
    ushort* ts1     = (ushort*)p;                       // 12.8 MB (bf16 [M][64])
    int2*   buk     = (int2*)p;                         // aliases ts1 (dead before mgemm1)
    ushort* h       = (ushort*)(p + 12800000);          // 12.8 MB (bf16 [M][64])
    ushort* ts2     = (ushort*)(p + 25600000);          // 9.6 MB (bf16 [M][48])

    hipMemsetAsync(bukcnt, 0, NBUK * sizeof(int), stream);

    // CSR build: bucket counts -> bases -> partition -> per-bucket LDS build
    bukhist_kernel<<<(N_EDGES + PART_CHUNK - 1) / PART_CHUNK, 256, 0, stream>>>(dst, bukcnt,
                                                                                N_EDGES);
    scanB_kernel<<<1, 256, 0, stream>>>(bukcnt, bbase, cursorA, rowptr);
    partA_kernel<<<(N_EDGES + PART_CHUNK - 1) / PART_CHUNK, 256, 0, stream>>>(src, dst, cursorA,
                                                                              buk, N_EDGES);
    bucket_kernel<<<NBUK, 512, 0, stream>>>(buk, bbase, rowptr, dis, csr, N_NODES);

    // weight pre-pack (B-fragment order)
    packW1_kernel<<<4, 256, 0, stream>>>(W1, Wb1);
    packW2_kernel<<<2, 256, 0, stream>>>(W2, Wb2);

    // layer 1
    mgemm1_kernel<<<(N_NODES + 127) / 128, 256, 0, stream>>>(x, Wb1, dis, ts1, N_NODES);
    gather64_kernel<<<(N_NODES * 8 + 255) / 256, 256, 0, stream>>>(rowptr, csr, ts1, dis, b1,
                                                                   h, N_NODES);

    // layer 2
    mgemm2_kernel<<<(N_NODES + 127) / 128, 256, 0, stream>>>(h, Wb2, dis, ts2, N_NODES);
    gather40_kernel<<<(N_NODES * 5 + 255) / 256, 256, 0, stream>>>(rowptr, csr, ts2, dis, b2,
                                                                   out, N_NODES);
    logsoftmax_kernel<<<(N_NODES + 255) / 256, 256, 0, stream>>>(out, N_NODES);
}

// Round 8
// 156.287 us; speedup vs baseline: 5.3219x; 1.0898x over previous
//
#include <hip/hip_runtime.h>

#define N_NODES 100000
#define N_EDGES 1600000
#define IN_DIM  128
#define HID_DIM 64
#define OUT_DIM 40

#define BUK_SHIFT 9
#define NBUK ((N_NODES + (1 << BUK_SHIFT) - 1) >> BUK_SHIFT)  // 196
#define PART_CHUNK 4096
#define PART_EPT 16     // PART_CHUNK / 256

typedef unsigned short ushort;
typedef unsigned int uint;
typedef __attribute__((ext_vector_type(8))) short bf16x8;
typedef __attribute__((ext_vector_type(4))) float f32x4;

// float -> bf16 bits, round-to-nearest-even
__device__ __forceinline__ ushort f2bf(float x) {
    uint u = __float_as_uint(x);
    uint r = ((u >> 16) & 1u) + 0x7fffu;
    return (ushort)((u + r) >> 16);
}

// ---------------- bucket histogram (196 counters, LDS-staged) ----------------
__global__ __launch_bounds__(256) void bukhist_kernel(const int* __restrict__ dst,
                                                      int* __restrict__ bukcnt, int E) {
    __shared__ int h[NBUK];
    const int t = threadIdx.x;
    for (int i = t; i < NBUK; i += 256) h[i] = 0;
    __syncthreads();
    const int e0 = blockIdx.x * PART_CHUNK;
#pragma unroll
    for (int i = 0; i < PART_EPT; ++i) {
        int e = e0 + t + i * 256;
        if (e < E) atomicAdd(&h[dst[e] >> BUK_SHIFT], 1);
    }
    __syncthreads();
    for (int i = t; i < NBUK; i += 256)
        if (h[i]) atomicAdd(&bukcnt[i], h[i]);
}

// ---------------- single-block scan of bucket counts -> bbase, cursorA ----------------
__global__ __launch_bounds__(256) void scanB_kernel(const int* __restrict__ bukcnt,
                                                    int* __restrict__ bbase,
                                                    int* __restrict__ cursorA,
                                                    int* __restrict__ rowptr) {
    __shared__ int sh[256];
    const int t = threadIdx.x;
    sh[t] = (t < NBUK) ? bukcnt[t] : 0;
    __syncthreads();
    for (int off = 1; off < 256; off <<= 1) {
        int v = (t >= off) ? sh[t - off] : 0;
        __syncthreads();
        sh[t] += v;
        __syncthreads();
    }
    if (t < NBUK) {
        int base = (t > 0) ? sh[t - 1] : 0;
        bbase[t] = base;
        cursorA[t] = base;
    }
    if (t == 0) { bbase[NBUK] = N_EDGES; rowptr[N_NODES] = N_EDGES; }
}

// ---------------- pass A: partition edges into dst-buckets ----------------
__global__ __launch_bounds__(256) void partA_kernel(const int* __restrict__ src,
                                                    const int* __restrict__ dst,
                                                    int* __restrict__ cursorA,
                                                    int2* __restrict__ buk, int E) {
    __shared__ int hist[NBUK];
    __shared__ int base[NBUK];
    const int t = threadIdx.x;
    const int e0 = blockIdx.x * PART_CHUNK;
    for (int i = t; i < NBUK; i += 256) hist[i] = 0;
    __syncthreads();
    int mys[PART_EPT], myd[PART_EPT];
#pragma unroll
    for (int i = 0; i < PART_EPT; ++i) {
        int e = e0 + t + i * 256;
        if (e < E) {
            mys[i] = src[e];
            myd[i] = dst[e];
            atomicAdd(&hist[myd[i] >> BUK_SHIFT], 1);
        } else {
            myd[i] = -1;
        }
    }
    __syncthreads();
    for (int i = t; i < NBUK; i += 256)
        base[i] = (hist[i] > 0) ? atomicAdd(&cursorA[i], hist[i]) : 0;
    __syncthreads();
    for (int i = t; i < NBUK; i += 256) hist[i] = 0;
    __syncthreads();
#pragma unroll
    for (int i = 0; i < PART_EPT; ++i) {
        if (myd[i] >= 0) {
            int b = myd[i] >> BUK_SHIFT;
            int pos = base[b] + atomicAdd(&hist[b], 1);
            buk[pos] = make_int2(mys[i], myd[i]);
        }
    }
}

// ---------------- per-bucket: node degrees + rowptr + dis + csr fill, all LDS ----------------
__global__ __launch_bounds__(512) void bucket_kernel(const int2* __restrict__ buk,
                                                     const int* __restrict__ bbase,
                                                     int* __restrict__ rowptr,
                                                     float* __restrict__ dis,
                                                     int* __restrict__ csr, int n) {
    __shared__ int cnt[512];
    __shared__ int pre[512];
    const int t = threadIdx.x;
    const int b = blockIdx.x;
    const int beg = bbase[b], end = bbase[b + 1];
    cnt[t] = 0;
    __syncthreads();
    for (int i = beg + t; i < end; i += 512)
        atomicAdd(&cnt[buk[i].y & 511], 1);
    __syncthreads();
    const int c = cnt[t];
    pre[t] = c;
    __syncthreads();
    for (int off = 1; off < 512; off <<= 1) {
        int v = (t >= off) ? pre[t - off] : 0;
        __syncthreads();
        pre[t] += v;
        __syncthreads();
    }
    const int ex = pre[t] - c;   // exclusive prefix within bucket
    const int v0 = (b << BUK_SHIFT) + t;
    if (v0 < n) {
        rowptr[v0] = beg + ex;
        dis[v0] = rsqrtf((float)c + 1.0f);
    }
    __syncthreads();
    cnt[t] = beg + ex;           // cursor (safe: each thread read only cnt[t] above)
    __syncthreads();
    for (int i = beg + t; i < end; i += 512) {
        int2 e = buk[i];
        int pos = atomicAdd(&cnt[e.y & 511], 1);
        csr[pos] = e.x;
    }
}

// ---------------- W pre-pack into B-fragment order ----------------
__global__ __launch_bounds__(256) void packW1_kernel(const float* __restrict__ W,
                                                     ushort* __restrict__ Wb) {
    int t = blockIdx.x * 256 + threadIdx.x;   // 4 ks * 4 ct * 64 = 1024
    int lane = t & 63;
    int ct = (t >> 6) & 3;
    int ks = t >> 8;
    int c = ct * 16 + (lane & 15);
    int kb = ks * 32 + ((lane >> 4) << 3);
#pragma unroll
    for (int j = 0; j < 8; ++j)
        Wb[t * 8 + j] = f2bf(W[(kb + j) * HID_DIM + c]);
}

__global__ __launch_bounds__(256) void packW2_kernel(const float* __restrict__ W,
                                                     ushort* __restrict__ Wb) {
    int t = blockIdx.x * 256 + threadIdx.x;   // 2 ks * 3 ct * 64 = 384
    if (t >= 384) return;
    int lane = t & 63;
    int f = t >> 6;          // 0..5
    int ks = f / 3, ct = f % 3;
    int c = ct * 16 + (lane & 15);
    int kb = ks * 32 + ((lane >> 4) << 3);
#pragma unroll
    for (int j = 0; j < 8; ++j)
        Wb[t * 8 + j] = (c < OUT_DIM) ? f2bf(W[(kb + j) * OUT_DIM + c]) : 0;
}

// ---------------- MFMA GEMM1: ts1(bf16[M][64]) = dis * (X(f32[M][128]) @ W1) ----------------
__global__ __launch_bounds__(256) void mgemm1_kernel(const float* __restrict__ X,
                                                     const ushort* __restrict__ Wb,
                                                     const float* __restrict__ dis,
                                                     ushort* __restrict__ Y, int M) {
    const int wave = threadIdx.x >> 6;
    const int lane = threadIdx.x & 63;
    const int r0 = blockIdx.x * 128 + wave * 32;
    const int la = lane & 15, lb = lane >> 4;

    f32x4 acc[2][4];
#pragma unroll
    for (int i = 0; i < 2; ++i)
#pragma unroll
        for (int j = 0; j < 4; ++j)
#pragma unroll
            for (int r = 0; r < 4; ++r) acc[i][j][r] = 0.0f;

    int ra0 = r0 + la;       if (ra0 >= M) ra0 = M - 1;
    int ra1 = r0 + 16 + la;  if (ra1 >= M) ra1 = M - 1;
    const float* xp0 = X + (long long)ra0 * IN_DIM + lb * 8;
    const float* xp1 = X + (long long)ra1 * IN_DIM + lb * 8;
    const bf16x8* wb = (const bf16x8*)Wb;

#pragma unroll
    for (int ks = 0; ks < 4; ++ks) {
        float4 x00 = *(const float4*)(xp0 + ks * 32);
        float4 x01 = *(const float4*)(xp0 + ks * 32 + 4);
        float4 x10 = *(const float4*)(xp1 + ks * 32);
        float4 x11 = *(const float4*)(xp1 + ks * 32 + 4);
        bf16x8 a0, a1;
        a0[0] = (short)f2bf(x00.x); a0[1] = (short)f2bf(x00.y);
        a0[2] = (short)f2bf(x00.z); a0[3] = (short)f2bf(x00.w);
        a0[4] = (short)f2bf(x01.x); a0[5] = (short)f2bf(x01.y);
        a0[6] = (short)f2bf(x01.z); a0[7] = (short)f2bf(x01.w);
        a1[0] = (short)f2bf(x10.x); a1[1] = (short)f2bf(x10.y);
        a1[2] = (short)f2bf(x10.z); a1[3] = (short)f2bf(x10.w);
        a1[4] = (short)f2bf(x11.x); a1[5] = (short)f2bf(x11.y);
        a1[6] = (short)f2bf(x11.z); a1[7] = (short)f2bf(x11.w);
#pragma unroll
        for (int ct = 0; ct < 4; ++ct) {
            bf16x8 b = wb[(ks * 4 + ct) * 64 + lane];
            acc[0][ct] = __builtin_amdgcn_mfma_f32_16x16x32_bf16(a0, b, acc[0][ct], 0, 0, 0);
            acc[1][ct] = __builtin_amdgcn_mfma_f32_16x16x32_bf16(a1, b, acc[1][ct], 0, 0, 0);
        }
    }

#pragma unroll
    for (int rt = 0; rt < 2; ++rt)
#pragma unroll
        for (int r = 0; r < 4; ++r) {
            int row = r0 + rt * 16 + lb * 4 + r;
            if (row < M) {
                float dv = dis[row];
#pragma unroll
                for (int ct = 0; ct < 4; ++ct)
                    Y[(long long)row * HID_DIM + ct * 16 + la] = f2bf(acc[rt][ct][r] * dv);
            }
        }
}

// ---------------- MFMA GEMM2: ts2(bf16[M][48]) = dis * (H(bf16[M][64]) @ W2) ----------------
__global__ __launch_bounds__(256) void mgemm2_kernel(const ushort* __restrict__ H,
                                                     const ushort* __restrict__ Wb,
                                                     const float* __restrict__ dis,
                                                     ushort* __restrict__ Y, int M) {
    const int wave = threadIdx.x >> 6;
    const int lane = threadIdx.x & 63;
    const int r0 = blockIdx.x * 128 + wave * 32;
    const int la = lane & 15, lb = lane >> 4;

    f32x4 acc[2][3];
#pragma unroll
    for (int i = 0; i < 2; ++i)
#pragma unroll
        for (int j = 0; j < 3; ++j)
#pragma unroll
            for (int r = 0; r < 4; ++r) acc[i][j][r] = 0.0f;

    int ra0 = r0 + la;       if (ra0 >= M) ra0 = M - 1;
    int ra1 = r0 + 16 + la;  if (ra1 >= M) ra1 = M - 1;
    const ushort* hp0 = H + (long long)ra0 * HID_DIM + lb * 8;
    const ushort* hp1 = H + (long long)ra1 * HID_DIM + lb * 8;
    const bf16x8* wb = (const bf16x8*)Wb;

#pragma unroll
    for (int ks = 0; ks < 2; ++ks) {
        bf16x8 a0 = *(const bf16x8*)(hp0 + ks * 32);
        bf16x8 a1 = *(const bf16x8*)(hp1 + ks * 32);
#pragma unroll
        for (int ct = 0; ct < 3; ++ct) {
            bf16x8 b = wb[(ks * 3 + ct) * 64 + lane];
            acc[0][ct] = __builtin_amdgcn_mfma_f32_16x16x32_bf16(a0, b, acc[0][ct], 0, 0, 0);
            acc[1][ct] = __builtin_amdgcn_mfma_f32_16x16x32_bf16(a1, b, acc[1][ct], 0, 0, 0);
        }
    }

#pragma unroll
    for (int rt = 0; rt < 2; ++rt)
#pragma unroll
        for (int r = 0; r < 4; ++r) {
            int row = r0 + rt * 16 + lb * 4 + r;
            if (row < M) {
                float dv = dis[row];
#pragma unroll
                for (int ct = 0; ct < 3; ++ct)
                    Y[(long long)row * 48 + ct * 16 + la] = f2bf(acc[rt][ct][r] * dv);
            }
        }
}

// ---------------- bf16 unpack-accumulate ----------------
__device__ __forceinline__ void add_bf8(float* acc, uint4 m) {
    acc[0] += __uint_as_float(m.x << 16);
    acc[1] += __uint_as_float(m.x & 0xffff0000u);
    acc[2] += __uint_as_float(m.y << 16);
    acc[3] += __uint_as_float(m.y & 0xffff0000u);
    acc[4] += __uint_as_float(m.z << 16);
    acc[5] += __uint_as_float(m.z & 0xffff0000u);
    acc[6] += __uint_as_float(m.w << 16);
    acc[7] += __uint_as_float(m.w & 0xffff0000u);
}

__device__ __forceinline__ void init_bf8(float* acc, uint4 m) {
    acc[0] = __uint_as_float(m.x << 16);
    acc[1] = __uint_as_float(m.x & 0xffff0000u);
    acc[2] = __uint_as_float(m.y << 16);
    acc[3] = __uint_as_float(m.y & 0xffff0000u);
    acc[4] = __uint_as_float(m.z << 16);
    acc[5] = __uint_as_float(m.z & 0xffff0000u);
    acc[6] = __uint_as_float(m.w << 16);
    acc[7] = __uint_as_float(m.w & 0xffff0000u);
}

// ---------------- gather 64 feats (bf16): 8 threads/node, unroll-4 MLP ----------------
__global__ __launch_bounds__(256) void gather64_kernel(const int* __restrict__ rowptr,
                                                       const int* __restrict__ csr,
                                                       const ushort* __restrict__ ts,
                                                       const float* __restrict__ dis,
                                                       const float* __restrict__ b,
                                                       ushort* __restrict__ h, int n) {
    int tid = blockIdx.x * 256 + threadIdx.x;
    int v = tid >> 3, q = tid & 7;
    if (v >= n) return;
    const uint4* tsv = (const uint4*)ts;
    int beg = rowptr[v], end = rowptr[v + 1];
    float acc[8];
    init_bf8(acc, tsv[v * 8 + q]);   // self-loop term
    int j = beg;
    for (; j + 3 < end; j += 4) {
        int u0 = csr[j], u1 = csr[j + 1], u2 = csr[j + 2], u3 = csr[j + 3];
        uint4 m0 = tsv[u0 * 8 + q];
        uint4 m1 = tsv[u1 * 8 + q];
        uint4 m2 = tsv[u2 * 8 + q];
        uint4 m3 = tsv[u3 * 8 + q];
        add_bf8(acc, m0); add_bf8(acc, m1); add_bf8(acc, m2); add_bf8(acc, m3);
    }
    for (; j < end; ++j) add_bf8(acc, tsv[csr[j] * 8 + q]);

    float dv = dis[v];
    float4 b0 = ((const float4*)b)[q * 2];
    float4 b1 = ((const float4*)b)[q * 2 + 1];
    float r0 = fmaxf(acc[0] * dv + b0.x, 0.0f);
    float r1 = fmaxf(acc[1] * dv + b0.y, 0.0f);
    float r2 = fmaxf(acc[2] * dv + b0.z, 0.0f);
    float r3 = fmaxf(acc[3] * dv + b0.w, 0.0f);
    float r4 = fmaxf(acc[4] * dv + b1.x, 0.0f);
    float r5 = fmaxf(acc[5] * dv + b1.y, 0.0f);
    float r6 = fmaxf(acc[6] * dv + b1.z, 0.0f);
    float r7 = fmaxf(acc[7] * dv + b1.w, 0.0f);
    uint4 o;
    o.x = ((uint)f2bf(r1) << 16) | f2bf(r0);
    o.y = ((uint)f2bf(r3) << 16) | f2bf(r2);
    o.z = ((uint)f2bf(r5) << 16) | f2bf(r4);
    o.w = ((uint)f2bf(r7) << 16) | f2bf(r6);
    ((uint4*)h)[v * 8 + q] = o;
}

// ---------------- fused gather 40 + log_softmax: block=320 (64 nodes), 5 thr/node ----------------
__global__ __launch_bounds__(320) void gather40ls_kernel(const int* __restrict__ rowptr,
                                                         const int* __restrict__ csr,
                                                         const ushort* __restrict__ ts,
                                                         const float* __restrict__ dis,
                                                         const float* __restrict__ b,
                                                         float* __restrict__ out, int n) {
    __shared__ float smax[64][5];
    __shared__ float ssum[64][5];
    const int t = threadIdx.x;
    const int vloc = t / 5, q = t - vloc * 5;
    const int v = blockIdx.x * 64 + vloc;
    const bool active = (v < n);

    float r[8];
    if (active) {
        const uint4* tsv = (const uint4*)ts;   // row stride 48 bf16 = 6 uint4
        int beg = rowptr[v], end = rowptr[v + 1];
        float acc[8];
        init_bf8(acc, tsv[v * 6 + q]);
        int j = beg;
        for (; j + 3 < end; j += 4) {
            int u0 = csr[j], u1 = csr[j + 1], u2 = csr[j + 2], u3 = csr[j + 3];
            uint4 m0 = tsv[u0 * 6 + q];
            uint4 m1 = tsv[u1 * 6 + q];
            uint4 m2 = tsv[u2 * 6 + q];
            uint4 m3 = tsv[u3 * 6 + q];
            add_bf8(acc, m0); add_bf8(acc, m1); add_bf8(acc, m2); add_bf8(acc, m3);
        }
        for (; j < end; ++j) add_bf8(acc, tsv[csr[j] * 6 + q]);

        float dv = dis[v];
        float4 b0 = ((const float4*)b)[q * 2];
        float4 b1 = ((const float4*)b)[q * 2 + 1];
        r[0] = acc[0] * dv + b0.x;
        r[1] = acc[1] * dv + b0.y;
        r[2] = acc[2] * dv + b0.z;
        r[3] = acc[3] * dv + b0.w;
        r[4] = acc[4] * dv + b1.x;
        r[5] = acc[5] * dv + b1.y;
        r[6] = acc[6] * dv + b1.z;
        r[7] = acc[7] * dv + b1.w;
    } else {
#pragma unroll
        for (int i = 0; i < 8; ++i) r[i] = 0.0f;
    }

    float m = r[0];
#pragma unroll
    for (int i = 1; i < 8; ++i) m = fmaxf(m, r[i]);
    smax[vloc][q] = m;
    __syncthreads();
    float gm = fmaxf(fmaxf(fmaxf(smax[vloc][0], smax[vloc][1]), fmaxf(smax[vloc][2], smax[vloc][3])),
                     smax[vloc][4]);
    float s = 0.0f;
#pragma unroll
    for (int i = 0; i < 8; ++i) s += __expf(r[i] - gm);
    ssum[vloc][q] = s;
    __syncthreads();
    float tot = ssum[vloc][0] + ssum[vloc][1] + ssum[vloc][2] + ssum[vloc][3] + ssum[vloc][4];
    float c = gm + __logf(tot);

    if (active) {
        float* rp = out + (long long)v * OUT_DIM + q * 8;
        float4 o0 = { r[0] - c, r[1] - c, r[2] - c, r[3] - c };
        float4 o1 = { r[4] - c, r[5] - c, r[6] - c, r[7] - c };
        ((float4*)rp)[0] = o0;
        ((float4*)rp)[1] = o1;
    }
}

extern "C" void kernel_launch(void* const* d_in, const int* in_sizes, int n_in,
                              void* d_out, int out_size, void* d_ws, size_t ws_size,
                              hipStream_t stream) {
    const float* x  = (const float*)d_in[0];
    const int*   ei = (const int*)d_in[1];
    const float* W1 = (const float*)d_in[2];
    const float* b1 = (const float*)d_in[3];
    const float* W2 = (const float*)d_in[4];
    const float* b2 = (const float*)d_in[5];
    float* out = (float*)d_out;

    const int* src = ei;
    const int* dst = ei + N_EDGES;

    // workspace layout (bytes) — regions verified non-overlapping:
    char* ws = (char*)d_ws;
    int*    rowptr  = (int*)ws;                         // [0, 400,004)
    float*  dis     = (float*)(ws + (512 << 10));       // [512K, 512K+400,000)
    int*    bukcnt  = (int*)(ws + (1024 << 10));        // 784 B
    int*    bbase   = (int*)(ws + (1028 << 10));        // 788 B
    int*    cursorA = (int*)(ws + (1032 << 10));        // 784 B
    ushort* Wb1     = (ushort*)(ws + (1036 << 10));     // 16 KB -> 1052K
    ushort* Wb2     = (ushort*)(ws + (1056 << 10));     // 6 KB  -> 1062K
    int*    csr     = (int*)(ws + (2048 << 10));        // 6.4 MB -> ~8.3 MB
    char*   p       = ws + (9216 << 10);                // 9 MB
    ushort* ts1     = (ushort*)p;                       // 12.8 MB (bf16 [M][64])
    int2*   buk     = (int2*)p;                         // aliases ts1 (dead before mgemm1)
    ushort* h       = (ushort*)(p + 12800000);          // 12.8 MB (bf16 [M][64])
    ushort* ts2     = (ushort*)(p + 25600000);          // 9.6 MB (bf16 [M][48])

    hipMemsetAsync(bukcnt, 0, NBUK * sizeof(int), stream);

    // CSR build: bucket counts -> bases -> partition -> per-bucket LDS build
    bukhist_kernel<<<(N_EDGES + PART_CHUNK - 1) / PART_CHUNK, 256, 0, stream>>>(dst, bukcnt,
                                                                                N_EDGES);
    scanB_kernel<<<1, 256, 0, stream>>>(bukcnt, bbase, cursorA, rowptr);
    partA_kernel<<<(N_EDGES + PART_CHUNK - 1) / PART_CHUNK, 256, 0, stream>>>(src, dst, cursorA,
                                                                              buk, N_EDGES);
    bucket_kernel<<<NBUK, 512, 0, stream>>>(buk, bbase, rowptr, dis, csr, N_NODES);

    // weight pre-pack (B-fragment order)
    packW1_kernel<<<4, 256, 0, stream>>>(W1, Wb1);
    packW2_kernel<<<2, 256, 0, stream>>>(W2, Wb2);

    // layer 1
    mgemm1_kernel<<<(N_NODES + 127) / 128, 256, 0, stream>>>(x, Wb1, dis, ts1, N_NODES);
    gather64_kernel<<<(N_NODES * 8 + 255) / 256, 256, 0, stream>>>(rowptr, csr, ts1, dis, b1,
                                                                   h, N_NODES);

    // layer 2 (log_softmax fused into the gather)
    mgemm2_kernel<<<(N_NODES + 127) / 128, 256, 0, stream>>>(h, Wb2, dis, ts2, N_NODES);
    gather40ls_kernel<<<(N_NODES + 63) / 64, 320, 0, stream>>>(rowptr, csr, ts2, dis, b2,
                                                               out, N_NODES);
}

// Round 9
// 147.031 us; speedup vs baseline: 5.6570x; 1.0630x over previous
//
#include <hip/hip_runtime.h>

#define N_NODES 100000
#define N_EDGES 1600000
#define IN_DIM  128
#define HID_DIM 64
#define OUT_DIM 40

#define BUK_SHIFT 9
#define NBUK ((N_NODES + (1 << BUK_SHIFT) - 1) >> BUK_SHIFT)  // 196
#define PART_CHUNK 4096
#define PART_EPT 16     // PART_CHUNK / 256

typedef unsigned short ushort;
typedef unsigned int uint;
typedef __attribute__((ext_vector_type(8))) short bf16x8;
typedef __attribute__((ext_vector_type(4))) float f32x4;

// float -> bf16 bits, round-to-nearest-even
__device__ __forceinline__ ushort f2bf(float x) {
    uint u = __float_as_uint(x);
    uint r = ((u >> 16) & 1u) + 0x7fffu;
    return (ushort)((u + r) >> 16);
}

// ---------------- bucket histogram (196 counters, LDS-staged) ----------------
__global__ __launch_bounds__(256) void bukhist_kernel(const int* __restrict__ dst,
                                                      int* __restrict__ bukcnt, int E) {
    __shared__ int h[NBUK];
    const int t = threadIdx.x;
    for (int i = t; i < NBUK; i += 256) h[i] = 0;
    __syncthreads();
    const int e0 = blockIdx.x * PART_CHUNK;
#pragma unroll
    for (int i = 0; i < PART_EPT; ++i) {
        int e = e0 + t + i * 256;
        if (e < E) atomicAdd(&h[dst[e] >> BUK_SHIFT], 1);
    }
    __syncthreads();
    for (int i = t; i < NBUK; i += 256)
        if (h[i]) atomicAdd(&bukcnt[i], h[i]);
}

// ---------------- single-block scan of bucket counts -> bbase, cursorA ----------------
__global__ __launch_bounds__(256) void scanB_kernel(const int* __restrict__ bukcnt,
                                                    int* __restrict__ bbase,
                                                    int* __restrict__ cursorA,
                                                    int* __restrict__ rowptr) {
    __shared__ int sh[256];
    const int t = threadIdx.x;
    sh[t] = (t < NBUK) ? bukcnt[t] : 0;
    __syncthreads();
    for (int off = 1; off < 256; off <<= 1) {
        int v = (t >= off) ? sh[t - off] : 0;
        __syncthreads();
        sh[t] += v;
        __syncthreads();
    }
    if (t < NBUK) {
        int base = (t > 0) ? sh[t - 1] : 0;
        bbase[t] = base;
        cursorA[t] = base;
    }
    if (t == 0) { bbase[NBUK] = N_EDGES; rowptr[N_NODES] = N_EDGES; }
}

// ---------------- pass A: partition edges into dst-buckets (packed uint) ----------------
// entry = src | ((dst & 511) << 17)   (src < 2^17, node-in-bucket 9 bits)
__global__ __launch_bounds__(256) void partA_kernel(const int* __restrict__ src,
                                                    const int* __restrict__ dst,
                                                    int* __restrict__ cursorA,
                                                    uint* __restrict__ buk, int E) {
    __shared__ int hist[NBUK];
    __shared__ int base[NBUK];
    const int t = threadIdx.x;
    const int e0 = blockIdx.x * PART_CHUNK;
    for (int i = t; i < NBUK; i += 256) hist[i] = 0;
    __syncthreads();
    int mys[PART_EPT], myd[PART_EPT];
#pragma unroll
    for (int i = 0; i < PART_EPT; ++i) {
        int e = e0 + t + i * 256;
        if (e < E) {
            mys[i] = src[e];
            myd[i] = dst[e];
            atomicAdd(&hist[myd[i] >> BUK_SHIFT], 1);
        } else {
            myd[i] = -1;
        }
    }
    __syncthreads();
    for (int i = t; i < NBUK; i += 256)
        base[i] = (hist[i] > 0) ? atomicAdd(&cursorA[i], hist[i]) : 0;
    __syncthreads();
    for (int i = t; i < NBUK; i += 256) hist[i] = 0;
    __syncthreads();
#pragma unroll
    for (int i = 0; i < PART_EPT; ++i) {
        if (myd[i] >= 0) {
            int b = myd[i] >> BUK_SHIFT;
            int pos = base[b] + atomicAdd(&hist[b], 1);
            buk[pos] = (uint)mys[i] | ((uint)(myd[i] & 511) << 17);
        }
    }
}

// ---------------- per-bucket: node degrees + rowptr + dis + csr fill, all LDS ----------------
__global__ __launch_bounds__(512) void bucket_kernel(const uint* __restrict__ buk,
                                                     const int* __restrict__ bbase,
                                                     int* __restrict__ rowptr,
                                                     float* __restrict__ dis,
                                                     int* __restrict__ csr, int n) {
    __shared__ int cnt[512];
    __shared__ int pre[512];
    const int t = threadIdx.x;
    const int b = blockIdx.x;
    const int beg = bbase[b], end = bbase[b + 1];
    cnt[t] = 0;
    __syncthreads();
    for (int i = beg + t; i < end; i += 512)
        atomicAdd(&cnt[(buk[i] >> 17) & 511], 1);
    __syncthreads();
    const int c = cnt[t];
    pre[t] = c;
    __syncthreads();
    for (int off = 1; off < 512; off <<= 1) {
        int v = (t >= off) ? pre[t - off] : 0;
        __syncthreads();
        pre[t] += v;
        __syncthreads();
    }
    const int ex = pre[t] - c;   // exclusive prefix within bucket
    const int v0 = (b << BUK_SHIFT) + t;
    if (v0 < n) {
        rowptr[v0] = beg + ex;
        dis[v0] = rsqrtf((float)c + 1.0f);
    }
    __syncthreads();
    cnt[t] = beg + ex;           // cursor
    __syncthreads();
    for (int i = beg + t; i < end; i += 512) {
        uint e = buk[i];
        int pos = atomicAdd(&cnt[(e >> 17) & 511], 1);
        csr[pos] = (int)(e & 0x1FFFFu);
    }
}

// ---------------- prep: packW1 (blocks 0-3) + packW2 (blocks 4-5) + zero bukcnt (block 6) ----
// Wb layout: frag (ks, ct) at ((ks*NCT + ct)*64 + lane)*8 ushorts
__global__ __launch_bounds__(256) void prep_kernel(const float* __restrict__ W1,
                                                   const float* __restrict__ W2,
                                                   ushort* __restrict__ Wb1,
                                                   ushort* __restrict__ Wb2,
                                                   int* __restrict__ bukcnt) {
    const int blk = blockIdx.x;
    if (blk < 4) {
        int t = blk * 256 + threadIdx.x;   // 0..1023: 4 ks * 4 ct * 64
        int lane = t & 63;
        int ct = (t >> 6) & 3;
        int ks = t >> 8;
        int c = ct * 16 + (lane & 15);
        int kb = ks * 32 + ((lane >> 4) << 3);
#pragma unroll
        for (int j = 0; j < 8; ++j)
            Wb1[t * 8 + j] = f2bf(W1[(kb + j) * HID_DIM + c]);
    } else if (blk < 6) {
        int t = (blk - 4) * 256 + threadIdx.x;   // 0..511 (384 used): 2 ks * 3 ct * 64
        if (t < 384) {
            int lane = t & 63;
            int f = t >> 6;          // 0..5
            int ks = f / 3, ct = f % 3;
            int c = ct * 16 + (lane & 15);
            int kb = ks * 32 + ((lane >> 4) << 3);
#pragma unroll
            for (int j = 0; j < 8; ++j)
                Wb2[t * 8 + j] = (c < OUT_DIM) ? f2bf(W2[(kb + j) * OUT_DIM + c]) : 0;
        }
    } else {
        int t = threadIdx.x;
        if (t < NBUK) bukcnt[t] = 0;
    }
}

// ---------------- MFMA GEMM1: ts1(bf16[M][64]) = dis * (X(f32[M][128]) @ W1) ----------------
__global__ __launch_bounds__(256) void mgemm1_kernel(const float* __restrict__ X,
                                                     const ushort* __restrict__ Wb,
                                                     const float* __restrict__ dis,
                                                     ushort* __restrict__ Y, int M) {
    const int wave = threadIdx.x >> 6;
    const int lane = threadIdx.x & 63;
    const int r0 = blockIdx.x * 128 + wave * 32;
    const int la = lane & 15, lb = lane >> 4;

    f32x4 acc[2][4];
#pragma unroll
    for (int i = 0; i < 2; ++i)
#pragma unroll
        for (int j = 0; j < 4; ++j)
#pragma unroll
            for (int r = 0; r < 4; ++r) acc[i][j][r] = 0.0f;

    int ra0 = r0 + la;       if (ra0 >= M) ra0 = M - 1;
    int ra1 = r0 + 16 + la;  if (ra1 >= M) ra1 = M - 1;
    const float* xp0 = X + (long long)ra0 * IN_DIM + lb * 8;
    const float* xp1 = X + (long long)ra1 * IN_DIM + lb * 8;
    const bf16x8* wb = (const bf16x8*)Wb;

#pragma unroll
    for (int ks = 0; ks < 4; ++ks) {
        float4 x00 = *(const float4*)(xp0 + ks * 32);
        float4 x01 = *(const float4*)(xp0 + ks * 32 + 4);
        float4 x10 = *(const float4*)(xp1 + ks * 32);
        float4 x11 = *(const float4*)(xp1 + ks * 32 + 4);
        bf16x8 a0, a1;
        a0[0] = (short)f2bf(x00.x); a0[1] = (short)f2bf(x00.y);
        a0[2] = (short)f2bf(x00.z); a0[3] = (short)f2bf(x00.w);
        a0[4] = (short)f2bf(x01.x); a0[5] = (short)f2bf(x01.y);
        a0[6] = (short)f2bf(x01.z); a0[7] = (short)f2bf(x01.w);
        a1[0] = (short)f2bf(x10.x); a1[1] = (short)f2bf(x10.y);
        a1[2] = (short)f2bf(x10.z); a1[3] = (short)f2bf(x10.w);
        a1[4] = (short)f2bf(x11.x); a1[5] = (short)f2bf(x11.y);
        a1[6] = (short)f2bf(x11.z); a1[7] = (short)f2bf(x11.w);
#pragma unroll
        for (int ct = 0; ct < 4; ++ct) {
            bf16x8 b = wb[(ks * 4 + ct) * 64 + lane];
            acc[0][ct] = __builtin_amdgcn_mfma_f32_16x16x32_bf16(a0, b, acc[0][ct], 0, 0, 0);
            acc[1][ct] = __builtin_amdgcn_mfma_f32_16x16x32_bf16(a1, b, acc[1][ct], 0, 0, 0);
        }
    }

#pragma unroll
    for (int rt = 0; rt < 2; ++rt)
#pragma unroll
        for (int r = 0; r < 4; ++r) {
            int row = r0 + rt * 16 + lb * 4 + r;
            if (row < M) {
                float dv = dis[row];
#pragma unroll
                for (int ct = 0; ct < 4; ++ct)
                    Y[(long long)row * HID_DIM + ct * 16 + la] = f2bf(acc[rt][ct][r] * dv);
            }
        }
}

// ---------------- MFMA GEMM2: ts2(bf16[M][48]) = dis * (H(bf16[M][64]) @ W2) ----------------
__global__ __launch_bounds__(256) void mgemm2_kernel(const ushort* __restrict__ H,
                                                     const ushort* __restrict__ Wb,
                                                     const float* __restrict__ dis,
                                                     ushort* __restrict__ Y, int M) {
    const int wave = threadIdx.x >> 6;
    const int lane = threadIdx.x & 63;
    const int r0 = blockIdx.x * 128 + wave * 32;
    const int la = lane & 15, lb = lane >> 4;

    f32x4 acc[2][3];
#pragma unroll
    for (int i = 0; i < 2; ++i)
#pragma unroll
        for (int j = 0; j < 3; ++j)
#pragma unroll
            for (int r = 0; r < 4; ++r) acc[i][j][r] = 0.0f;

    int ra0 = r0 + la;       if (ra0 >= M) ra0 = M - 1;
    int ra1 = r0 + 16 + la;  if (ra1 >= M) ra1 = M - 1;
    const ushort* hp0 = H + (long long)ra0 * HID_DIM + lb * 8;
    const ushort* hp1 = H + (long long)ra1 * HID_DIM + lb * 8;
    const bf16x8* wb = (const bf16x8*)Wb;

#pragma unroll
    for (int ks = 0; ks < 2; ++ks) {
        bf16x8 a0 = *(const bf16x8*)(hp0 + ks * 32);
        bf16x8 a1 = *(const bf16x8*)(hp1 + ks * 32);
#pragma unroll
        for (int ct = 0; ct < 3; ++ct) {
            bf16x8 b = wb[(ks * 3 + ct) * 64 + lane];
            acc[0][ct] = __builtin_amdgcn_mfma_f32_16x16x32_bf16(a0, b, acc[0][ct], 0, 0, 0);
            acc[1][ct] = __builtin_amdgcn_mfma_f32_16x16x32_bf16(a1, b, acc[1][ct], 0, 0, 0);
        }
    }

#pragma unroll
    for (int rt = 0; rt < 2; ++rt)
#pragma unroll
        for (int r = 0; r < 4; ++r) {
            int row = r0 + rt * 16 + lb * 4 + r;
            if (row < M) {
                float dv = dis[row];
#pragma unroll
                for (int ct = 0; ct < 3; ++ct)
                    Y[(long long)row * 48 + ct * 16 + la] = f2bf(acc[rt][ct][r] * dv);
            }
        }
}

// ---------------- bf16 unpack-accumulate ----------------
__device__ __forceinline__ void add_bf8(float* acc, uint4 m) {
    acc[0] += __uint_as_float(m.x << 16);
    acc[1] += __uint_as_float(m.x & 0xffff0000u);
    acc[2] += __uint_as_float(m.y << 16);
    acc[3] += __uint_as_float(m.y & 0xffff0000u);
    acc[4] += __uint_as_float(m.z << 16);
    acc[5] += __uint_as_float(m.z & 0xffff0000u);
    acc[6] += __uint_as_float(m.w << 16);
    acc[7] += __uint_as_float(m.w & 0xffff0000u);
}

__device__ __forceinline__ void init_bf8(float* acc, uint4 m) {
    acc[0] = __uint_as_float(m.x << 16);
    acc[1] = __uint_as_float(m.x & 0xffff0000u);
    acc[2] = __uint_as_float(m.y << 16);
    acc[3] = __uint_as_float(m.y & 0xffff0000u);
    acc[4] = __uint_as_float(m.z << 16);
    acc[5] = __uint_as_float(m.z & 0xffff0000u);
    acc[6] = __uint_as_float(m.w << 16);
    acc[7] = __uint_as_float(m.w & 0xffff0000u);
}

// ---------------- gather 64 feats: 8 thr/node, csr-prefetch pipelined ----------------
__global__ __launch_bounds__(256) void gather64_kernel(const int* __restrict__ rowptr,
                                                       const int* __restrict__ csr,
                                                       const ushort* __restrict__ ts,
                                                       const float* __restrict__ dis,
                                                       const float* __restrict__ b,
                                                       ushort* __restrict__ h, int n) {
    int tid = blockIdx.x * 256 + threadIdx.x;
    int v = tid >> 3, q = tid & 7;
    if (v >= n) return;
    const uint4* tsv = (const uint4*)ts;
    int beg = rowptr[v], end = rowptr[v + 1];
    float acc[8];
    init_bf8(acc, tsv[v * 8 + q]);   // self-loop term
    int j = beg;
    if (j + 3 < end) {
        int c0 = csr[j], c1 = csr[j + 1], c2 = csr[j + 2], c3 = csr[j + 3];
        j += 4;
        for (; j + 3 < end; j += 4) {
            int n0 = csr[j], n1 = csr[j + 1], n2 = csr[j + 2], n3 = csr[j + 3];
            uint4 m0 = tsv[c0 * 8 + q];
            uint4 m1 = tsv[c1 * 8 + q];
            uint4 m2 = tsv[c2 * 8 + q];
            uint4 m3 = tsv[c3 * 8 + q];
            add_bf8(acc, m0); add_bf8(acc, m1); add_bf8(acc, m2); add_bf8(acc, m3);
            c0 = n0; c1 = n1; c2 = n2; c3 = n3;
        }
        uint4 m0 = tsv[c0 * 8 + q];
        uint4 m1 = tsv[c1 * 8 + q];
        uint4 m2 = tsv[c2 * 8 + q];
        uint4 m3 = tsv[c3 * 8 + q];
        add_bf8(acc, m0); add_bf8(acc, m1); add_bf8(acc, m2); add_bf8(acc, m3);
    }
    for (; j < end; ++j) add_bf8(acc, tsv[csr[j] * 8 + q]);

    float dv = dis[v];
    float4 b0 = ((const float4*)b)[q * 2];
    float4 b1 = ((const float4*)b)[q * 2 + 1];
    float r0 = fmaxf(acc[0] * dv + b0.x, 0.0f);
    float r1 = fmaxf(acc[1] * dv + b0.y, 0.0f);
    float r2 = fmaxf(acc[2] * dv + b0.z, 0.0f);
    float r3 = fmaxf(acc[3] * dv + b0.w, 0.0f);
    float r4 = fmaxf(acc[4] * dv + b1.x, 0.0f);
    float r5 = fmaxf(acc[5] * dv + b1.y, 0.0f);
    float r6 = fmaxf(acc[6] * dv + b1.z, 0.0f);
    float r7 = fmaxf(acc[7] * dv + b1.w, 0.0f);
    uint4 o;
    o.x = ((uint)f2bf(r1) << 16) | f2bf(r0);
    o.y = ((uint)f2bf(r3) << 16) | f2bf(r2);
    o.z = ((uint)f2bf(r5) << 16) | f2bf(r4);
    o.w = ((uint)f2bf(r7) << 16) | f2bf(r6);
    ((uint4*)h)[v * 8 + q] = o;
}

// ---------------- fused gather 40 + log_softmax: block=320 (64 nodes), pipelined ----------------
__global__ __launch_bounds__(320) void gather40ls_kernel(const int* __restrict__ rowptr,
                                                         const int* __restrict__ csr,
                                                         const ushort* __restrict__ ts,
                                                         const float* __restrict__ dis,
                                                         const float* __restrict__ b,
                                                         float* __restrict__ out, int n) {
    __shared__ float smax[64][5];
    __shared__ float ssum[64][5];
    const int t = threadIdx.x;
    const int vloc = t / 5, q = t - vloc * 5;
    const int v = blockIdx.x * 64 + vloc;
    const bool active = (v < n);

    float r[8];
    if (active) {
        const uint4* tsv = (const uint4*)ts;   // row stride 48 bf16 = 6 uint4
        int beg = rowptr[v], end = rowptr[v + 1];
        float acc[8];
        init_bf8(acc, tsv[v * 6 + q]);
        int j = beg;
        if (j + 3 < end) {
            int c0 = csr[j], c1 = csr[j + 1], c2 = csr[j + 2], c3 = csr[j + 3];
            j += 4;
            for (; j + 3 < end; j += 4) {
                int n0 = csr[j], n1 = csr[j + 1], n2 = csr[j + 2], n3 = csr[j + 3];
                uint4 m0 = tsv[c0 * 6 + q];
                uint4 m1 = tsv[c1 * 6 + q];
                uint4 m2 = tsv[c2 * 6 + q];
                uint4 m3 = tsv[c3 * 6 + q];
                add_bf8(acc, m0); add_bf8(acc, m1); add_bf8(acc, m2); add_bf8(acc, m3);
                c0 = n0; c1 = n1; c2 = n2; c3 = n3;
            }
            uint4 m0 = tsv[c0 * 6 + q];
            uint4 m1 = tsv[c1 * 6 + q];
            uint4 m2 = tsv[c2 * 6 + q];
            uint4 m3 = tsv[c3 * 6 + q];
            add_bf8(acc, m0); add_bf8(acc, m1); add_bf8(acc, m2); add_bf8(acc, m3);
        }
        for (; j < end; ++j) add_bf8(acc, tsv[csr[j] * 6 + q]);

        float dv = dis[v];
        float4 b0 = ((const float4*)b)[q * 2];
        float4 b1 = ((const float4*)b)[q * 2 + 1];
        r[0] = acc[0] * dv + b0.x;
        r[1] = acc[1] * dv + b0.y;
        r[2] = acc[2] * dv + b0.z;
        r[3] = acc[3] * dv + b0.w;
        r[4] = acc[4] * dv + b1.x;
        r[5] = acc[5] * dv + b1.y;
        r[6] = acc[6] * dv + b1.z;
        r[7] = acc[7] * dv + b1.w;
    } else {
#pragma unroll
        for (int i = 0; i < 8; ++i) r[i] = 0.0f;
    }

    float m = r[0];
#pragma unroll
    for (int i = 1; i < 8; ++i) m = fmaxf(m, r[i]);
    smax[vloc][q] = m;
    __syncthreads();
    float gm = fmaxf(fmaxf(fmaxf(smax[vloc][0], smax[vloc][1]), fmaxf(smax[vloc][2], smax[vloc][3])),
                     smax[vloc][4]);
    float s = 0.0f;
#pragma unroll
    for (int i = 0; i < 8; ++i) s += __expf(r[i] - gm);
    ssum[vloc][q] = s;
    __syncthreads();
    float tot = ssum[vloc][0] + ssum[vloc][1] + ssum[vloc][2] + ssum[vloc][3] + ssum[vloc][4];
    float c = gm + __logf(tot);

    if (active) {
        float* rp = out + (long long)v * OUT_DIM + q * 8;
        float4 o0 = { r[0] - c, r[1] - c, r[2] - c, r[3] - c };
        float4 o1 = { r[4] - c, r[5] - c, r[6] - c, r[7] - c };
        ((float4*)rp)[0] = o0;
        ((float4*)rp)[1] = o1;
    }
}

extern "C" void kernel_launch(void* const* d_in, const int* in_sizes, int n_in,
                              void* d_out, int out_size, void* d_ws, size_t ws_size,
                              hipStream_t stream) {
    const float* x  = (const float*)d_in[0];
    const int*   ei = (const int*)d_in[1];
    const float* W1 = (const float*)d_in[2];
    const float* b1 = (const float*)d_in[3];
    const float* W2 = (const float*)d_in[4];
    const float* b2 = (const float*)d_in[5];
    float* out = (float*)d_out;

    const int* src = ei;
    const int* dst = ei + N_EDGES;

    // workspace layout (bytes) — regions verified non-overlapping:
    char* ws = (char*)d_ws;
    int*    rowptr  = (int*)ws;                         // [0, 400,004)
    float*  dis     = (float*)(ws + (512 << 10));       // [512K, 512K+400,000)
    int*    bukcnt  = (int*)(ws + (1024 << 10));        // 784 B
    int*    bbase   = (int*)(ws + (1028 << 10));        // 788 B
    int*    cursorA = (int*)(ws + (1032 << 10));        // 784 B
    ushort* Wb1     = (ushort*)(ws + (1036 << 10));     // 16 KB -> 1052K
    ushort* Wb2     = (ushort*)(ws + (1056 << 10));     // 6 KB  -> 1062K
    int*    csr     = (int*)(ws + (2048 << 10));        // 6.4 MB -> ~8.3 MB
    char*   p       = ws + (9216 << 10);                // 9 MB
    ushort* ts1     = (ushort*)p;                       // 12.8 MB (bf16 [M][64])
    uint*   buk     = (uint*)p;                         // 6.4 MB, aliases ts1 (dead before mgemm1)
    ushort* h       = (ushort*)(p + 12800000);          // 12.8 MB (bf16 [M][64])
    ushort* ts2     = (ushort*)(p + 25600000);          // 9.6 MB (bf16 [M][48])

    // prep: packW1/packW2 + zero bukcnt (one launch)
    prep_kernel<<<7, 256, 0, stream>>>(W1, W2, Wb1, Wb2, bukcnt);

    // CSR build: bucket counts -> bases -> partition -> per-bucket LDS build
    bukhist_kernel<<<(N_EDGES + PART_CHUNK - 1) / PART_CHUNK, 256, 0, stream>>>(dst, bukcnt,
                                                                                N_EDGES);
    scanB_kernel<<<1, 256, 0, stream>>>(bukcnt, bbase, cursorA, rowptr);
    partA_kernel<<<(N_EDGES + PART_CHUNK - 1) / PART_CHUNK, 256, 0, stream>>>(src, dst, cursorA,
                                                                              buk, N_EDGES);
    bucket_kernel<<<NBUK, 512, 0, stream>>>(buk, bbase, rowptr, dis, csr, N_NODES);

    // layer 1
    mgemm1_kernel<<<(N_NODES + 127) / 128, 256, 0, stream>>>(x, Wb1, dis, ts1, N_NODES);
    gather64_kernel<<<(N_NODES * 8 + 255) / 256, 256, 0, stream>>>(rowptr, csr, ts1, dis, b1,
                                                                   h, N_NODES);

    // layer 2 (log_softmax fused into the gather)
    mgemm2_kernel<<<(N_NODES + 127) / 128, 256, 0, stream>>>(h, Wb2, dis, ts2, N_NODES);
    gather40ls_kernel<<<(N_NODES + 63) / 64, 320, 0, stream>>>(rowptr, csr, ts2, dis, b2,
                                                               out, N_NODES);
}